// Round 13
// baseline (223.469 us; speedup 1.0000x reference)
//
#include <hip/hip_runtime.h>
#include <math.h>

#define NB 4
#define CH 256
#define NHEADS 4
#define HC 64
#define NT 2304    // 48*48
#define KSEG 1152  // keys per segment (split-K x2)
#define NSEG 18    // 64-key chunks per segment

typedef _Float16 f16;
typedef _Float16 f16x4 __attribute__((ext_vector_type(4)));
typedef _Float16 f16x8 __attribute__((ext_vector_type(8)));
typedef float f32x4 __attribute__((ext_vector_type(4)));
typedef float f32x16 __attribute__((ext_vector_type(16)));

#define MFMA16(a, b, c) __builtin_amdgcn_mfma_f32_16x16x32_f16(a, b, c, 0, 0, 0)
#define MFMA32(a, b, c) __builtin_amdgcn_mfma_f32_32x32x16_f16(a, b, c, 0, 0, 0)

__device__ __forceinline__ void gload_lds16(const void* g, void* l) {
    __builtin_amdgcn_global_load_lds(
        (const __attribute__((address_space(1))) unsigned int*)g,
        (__attribute__((address_space(3))) unsigned int*)l, 16, 0, 0);
}

__device__ __forceinline__ unsigned pkh(float a, float b) {
    auto r = __builtin_amdgcn_cvt_pkrtz(a, b);   // __fp16 ext_vector(2)
    return __builtin_bit_cast(unsigned, r);
}
__device__ __forceinline__ void swap32(unsigned& a, unsigned& b) {
    asm volatile("v_permlane32_swap_b32 %0, %1" : "+v"(a), "+v"(b));
}

// ---------------------------------------------------------------------------
// Fused K/Q/V projection reading x directly (unchanged from R9-R12).
// ---------------------------------------------------------------------------
__global__ __launch_bounds__(256) void proj_qkv_mfma(
    const float* __restrict__ wk, const float* __restrict__ bk,
    const float* __restrict__ wq, const float* __restrict__ bq,
    const float* __restrict__ wv, const float* __restrict__ bv,
    const float* __restrict__ X,
    f16* __restrict__ Kt, f16* __restrict__ Qt, f16* __restrict__ Vg)
{
    const int t = threadIdx.x, l = t & 63, w = t >> 6;
    const int lm = l & 15, lg = l >> 4;
    const int n0 = blockIdx.x * 64;
    const int sel = blockIdx.y;
    const int b = blockIdx.z;

    const float* W  = sel == 0 ? wk : (sel == 1 ? wq : wv);
    const float* Bi = sel == 0 ? bk : (sel == 1 ? bq : bv);

    f32x4 acc[4][4] = {};

#pragma unroll 2
    for (int ks = 0; ks < 8; ++ks) {
        f16x8 bf[4];
#pragma unroll
        for (int nt = 0; nt < 4; ++nt) {
            const float* xp = &X[((size_t)b * CH + ks * 32 + lg * 8) * NT
                                 + n0 + nt * 16 + lm];
            f16x8 v;
#pragma unroll
            for (int j = 0; j < 8; ++j) v[j] = (f16)xp[(size_t)j * NT];
            bf[nt] = v;
        }
#pragma unroll
        for (int h = 0; h < 4; ++h) {
            const float* wp = &W[(size_t)(h * 64 + w * 16 + lm) * CH + ks * 32 + lg * 8];
            const float4 wa = *reinterpret_cast<const float4*>(wp);
            const float4 wb = *reinterpret_cast<const float4*>(wp + 4);
            const f16x8 a = {(f16)wa.x, (f16)wa.y, (f16)wa.z, (f16)wa.w,
                             (f16)wb.x, (f16)wb.y, (f16)wb.z, (f16)wb.w};
#pragma unroll
            for (int nt = 0; nt < 4; ++nt)
                acc[h][nt] = MFMA16(a, bf[nt], acc[h][nt]);
        }
    }

    const int c_base = w * 16 + lg * 4;
#pragma unroll
    for (int h = 0; h < 4; ++h) {
        const float4 b4 = *reinterpret_cast<const float4*>(&Bi[h * 64 + c_base]);
        const float bb[4] = {b4.x, b4.y, b4.z, b4.w};
        if (sel < 2) {
            f16* Out = sel == 0 ? Kt : Qt;
#pragma unroll
            for (int nt = 0; nt < 4; ++nt) {
                const int n = n0 + nt * 16 + lm;
                f16x4 o = {(f16)(acc[h][nt][0] + bb[0]), (f16)(acc[h][nt][1] + bb[1]),
                           (f16)(acc[h][nt][2] + bb[2]), (f16)(acc[h][nt][3] + bb[3])};
                *reinterpret_cast<f16x4*>(
                    &Out[((size_t)((b * NHEADS + h) * NT + n)) * HC + c_base]) = o;
            }
        } else {
#pragma unroll
            for (int nt = 0; nt < 4; ++nt) {
                const int n = n0 + nt * 16 + lm;
#pragma unroll
                for (int r = 0; r < 4; ++r)
                    Vg[((size_t)((b * NHEADS + h) * HC + c_base + r)) * NT + n] =
                        (f16)(acc[h][nt][r] + bb[r]);
            }
        }
    }
}

// ---------------------------------------------------------------------------
// ABLATION of R9's attn_split2 (65 µs reference).  template<V>:
//   V0 = full   V1 = no-stage   V2 = no-exp/max   V3 = skeleton (no softmax)
// All variants identical structure/grid/barriers; all write Ot (V0 last).
// ---------------------------------------------------------------------------
template<int V>
__global__ __launch_bounds__(256) void attn_abl(
    const f16* __restrict__ Kt, const f16* __restrict__ Qt,
    const f16* __restrict__ Vg, f16* __restrict__ Ot)
{
    __shared__ f16 SM[2][2][4096];   // [seg][K/V][64 rows x 64c]
    __shared__ float Ml[2][64], Ll[2][64];

    const int t = threadIdx.x, l = t & 63, w = t >> 6;
    const int col = l & 31, hi = l >> 5;
    const int qh = w & 1, sg = w >> 1;

    const int bid = blockIdx.x;
    const int xcd = bid & 7, idx = bid >> 3;
    const int bh  = 2 * xcd + (idx >= 36 ? 1 : 0);
    const int qt  = idx >= 36 ? idx - 36 : idx;
    const int b = bh >> 2, h = bh & 3;
    const int m0 = qt * 64;

    const size_t bhs = (size_t)(b * NHEADS + h);
    const f16* Kb = Kt + bhs * NT * HC;
    const f16* Qb = Qt + bhs * NT * HC;
    const f16* Vb = Vg + bhs * HC * NT;

    const int srow = l >> 3, su = l & 7, sx = su ^ srow;

    const int q = m0 + qh * 32 + col;
    f16x8 qf[4];
#pragma unroll
    for (int cs = 0; cs < 4; ++cs)
        qf[cs] = *reinterpret_cast<const f16x8*>(
            &Qb[(size_t)q * HC + cs * 16 + hi * 8]);

    const f32x16 Z16 = {0,0,0,0,0,0,0,0,0,0,0,0,0,0,0,0};
    f32x16 acc0 = Z16, acc1 = Z16;
    float m_run = -3.0e38f, l_run = 0.0f;

    const int kbase = sg * KSEG;

    auto stage = [&](int kc) {
        if constexpr (V == 1) { (void)kc; return; }
        if (qh == 0) {
            const char* src = (const char*)(Kb + (size_t)kc * HC);
            char* dst = (char*)&SM[sg][0][0];
#pragma unroll
            for (int g = 0; g < 8; ++g)
                gload_lds16(src + (size_t)(g * 8 + srow) * 128 + (sx << 4),
                            dst + g * 1024);
        } else {
            const char* src = (const char*)Vb + (size_t)kc * 2;
            char* dst = (char*)&SM[sg][1][0];
#pragma unroll
            for (int g = 0; g < 8; ++g)
                gload_lds16(src + (size_t)(g * 8 + srow) * (NT * 2) + (sx << 4),
                            dst + g * 1024);
        }
    };

    auto rd = [&](const f16* base, int row, int u) -> f16x8 {
        return *reinterpret_cast<const f16x8*>(
            base + row * 64 + ((u ^ (row & 7)) << 3));
    };

    stage(kbase);
    __syncthreads();

    for (int i = 0; i < NSEG; ++i) {
        const f16* Kc = &SM[sg][0][0];
        const f16* Vc = &SM[sg][1][0];

        // ---- QK^T -------------------------------------------------------
        f32x16 s0 = Z16, s1 = Z16;
#pragma unroll
        for (int cs = 0; cs < 4; ++cs) {
            const f16x8 k0 = rd(Kc, col,      cs * 2 + hi);
            const f16x8 k1 = rd(Kc, 32 + col, cs * 2 + hi);
            s0 = MFMA32(k0, qf[cs], s0);
            s1 = MFMA32(k1, qf[cs], s1);
        }

        float p0[16], p1[16];
        if constexpr (V == 0) {
            // ---- full softmax: tree max, shfl, defer-max, 32 exps -------
            float m8[8];
#pragma unroll
            for (int j = 0; j < 8; ++j)
                m8[j] = fmaxf(fmaxf(s0[2 * j], s0[2 * j + 1]),
                              fmaxf(s1[2 * j], s1[2 * j + 1]));
            float cm = fmaxf(fmaxf(fmaxf(m8[0], m8[1]), fmaxf(m8[2], m8[3])),
                             fmaxf(fmaxf(m8[4], m8[5]), fmaxf(m8[6], m8[7])));
            cm = fmaxf(cm, __shfl_xor(cm, 32));
            if (!__all(cm <= m_run + 8.0f)) {
                const float mN = fmaxf(m_run, cm);
                const float fac = __expf(m_run - mN);
#pragma unroll
                for (int r = 0; r < 16; ++r) { acc0[r] *= fac; acc1[r] *= fac; }
                l_run *= fac;
                m_run = mN;
            }
            float ps0 = 0.f, ps1 = 0.f, ps2 = 0.f, ps3 = 0.f;
#pragma unroll
            for (int r = 0; r < 4; ++r) {
                p0[r]      = __expf(s0[r]      - m_run); ps0 += p0[r];
                p0[r + 4]  = __expf(s0[r + 4]  - m_run); ps1 += p0[r + 4];
                p0[r + 8]  = __expf(s0[r + 8]  - m_run); ps2 += p0[r + 8];
                p0[r + 12] = __expf(s0[r + 12] - m_run); ps3 += p0[r + 12];
                p1[r]      = __expf(s1[r]      - m_run); ps0 += p1[r];
                p1[r + 4]  = __expf(s1[r + 4]  - m_run); ps1 += p1[r + 4];
                p1[r + 8]  = __expf(s1[r + 8]  - m_run); ps2 += p1[r + 8];
                p1[r + 12] = __expf(s1[r + 12] - m_run); ps3 += p1[r + 12];
            }
            l_run += (ps0 + ps1) + (ps2 + ps3);
        } else if constexpr (V == 1 || V == 2) {
            // ---- V2 (and V1): raw scores, no max/exp chain --------------
            float ps = 0.f;
#pragma unroll
            for (int r = 0; r < 16; ++r) {
                p0[r] = s0[r]; p1[r] = s1[r];
                ps += p0[r] + p1[r];
            }
            l_run += ps;
        } else {
            // ---- V3: keep QK^T live, no P at all ------------------------
            float keep = s0[0] + s1[0];
            asm volatile("" :: "v"(keep));
        }

        union BU { unsigned u[4]; f16x8 v; };
        BU fr[4];
        if constexpr (V != 3) {
            // ---- P -> f16 B-frags (pkrtz + permlane32_swap) -------------
            unsigned a0[8], a1[8];
#pragma unroll
            for (int j = 0; j < 8; ++j) {
                a0[j] = pkh(p0[2 * j], p0[2 * j + 1]);
                a1[j] = pkh(p1[2 * j], p1[2 * j + 1]);
            }
            swap32(a0[0], a0[2]); swap32(a0[1], a0[3]);
            swap32(a0[4], a0[6]); swap32(a0[5], a0[7]);
            swap32(a1[0], a1[2]); swap32(a1[1], a1[3]);
            swap32(a1[4], a1[6]); swap32(a1[5], a1[7]);
            fr[0].u[0] = a0[0]; fr[0].u[1] = a0[1]; fr[0].u[2] = a0[2]; fr[0].u[3] = a0[3];
            fr[1].u[0] = a0[4]; fr[1].u[1] = a0[5]; fr[1].u[2] = a0[6]; fr[1].u[3] = a0[7];
            fr[2].u[0] = a1[0]; fr[2].u[1] = a1[1]; fr[2].u[2] = a1[2]; fr[2].u[3] = a1[3];
            fr[3].u[0] = a1[4]; fr[3].u[1] = a1[5]; fr[3].u[2] = a1[6]; fr[3].u[3] = a1[7];
        } else {
#pragma unroll
            for (int kk = 0; kk < 4; ++kk) fr[kk].v = qf[kk];
        }

        // ---- O += V @ P -------------------------------------------------
#pragma unroll
        for (int kk = 0; kk < 4; ++kk) {
            const f16x8 v0 = rd(Vc, col,      kk * 2 + hi);
            const f16x8 v1 = rd(Vc, 32 + col, kk * 2 + hi);
            acc0 = MFMA32(v0, fr[kk].v, acc0);
            acc1 = MFMA32(v1, fr[kk].v, acc1);
        }

        __syncthreads();
        if (i + 1 < NSEG) {
            stage(kbase + (i + 1) * 64);
            __syncthreads();
        }
    }

    // ---- publish + 2-way merge (identical for all variants) -------------
    float* Part = (float*)&SM[0][0][0];
    const float l_full = l_run + __shfl_xor(l_run, 32);
    __syncthreads();
    if (hi == 0) {
        Ml[sg][qh * 32 + col] = m_run;
        Ll[sg][qh * 32 + col] = l_full;
    }
    {
        float* row = Part + ((size_t)(sg * 64 + qh * 32 + col)) * 64;
#pragma unroll
        for (int rq = 0; rq < 4; ++rq) {
            const int c0 = rq * 8 + hi * 4;
            f32x4 o0 = {acc0[rq * 4 + 0], acc0[rq * 4 + 1],
                        acc0[rq * 4 + 2], acc0[rq * 4 + 3]};
            f32x4 o1 = {acc1[rq * 4 + 0], acc1[rq * 4 + 1],
                        acc1[rq * 4 + 2], acc1[rq * 4 + 3]};
            *reinterpret_cast<f32x4*>(row + c0) = o0;
            *reinterpret_cast<f32x4*>(row + 32 + c0) = o1;
        }
    }
    __syncthreads();
    {
        const int qq = t >> 2, c0 = (t & 3) * 16;
        const float mA = Ml[0][qq], mB = Ml[1][qq];
        const float M = fmaxf(mA, mB);
        const float wA = __expf(mA - M), wB = __expf(mB - M);
        const float inv = 1.0f / (wA * Ll[0][qq] + wB * Ll[1][qq]);
        const float* r0 = Part + (size_t)qq * 64;
        const float* r1 = Part + (size_t)(64 + qq) * 64;
        f16* dst = &Ot[((size_t)(b * NT + m0 + qq)) * CH + h * HC + c0];
#pragma unroll
        for (int j = 0; j < 16; j += 4) {
            const f32x4 aA = *reinterpret_cast<const f32x4*>(r0 + c0 + j);
            const f32x4 aB = *reinterpret_cast<const f32x4*>(r1 + c0 + j);
            f16x4 o = {(f16)((wA * aA[0] + wB * aB[0]) * inv),
                       (f16)((wA * aA[1] + wB * aB[1]) * inv),
                       (f16)((wA * aA[2] + wB * aB[2]) * inv),
                       (f16)((wA * aA[3] + wB * aB[3]) * inv)};
            *reinterpret_cast<f16x4*>(dst + j) = o;
        }
    }
}

// ---------------------------------------------------------------------------
// Final conv1x1 (unchanged). grid (36, 4, 4).
// ---------------------------------------------------------------------------
__global__ __launch_bounds__(256) void out_gemm_mfma(
    const float* __restrict__ wo, const float* __restrict__ bo,
    const f16* __restrict__ Ot, float* __restrict__ Y)
{
    const int t = threadIdx.x, l = t & 63, w = t >> 6;
    const int lm = l & 15, lg = l >> 4;
    const int n0 = blockIdx.x * 64;
    const int o0 = blockIdx.y * 64;
    const int b = blockIdx.z;

    f32x4 acc[4] = {{0.f,0.f,0.f,0.f},{0.f,0.f,0.f,0.f},
                    {0.f,0.f,0.f,0.f},{0.f,0.f,0.f,0.f}};
    const int o_row = o0 + w * 16 + lm;

#pragma unroll
    for (int ks = 0; ks < 8; ++ks) {
        const float* wp = &wo[(size_t)o_row * CH + ks * 32 + lg * 8];
        const float4 wa = *reinterpret_cast<const float4*>(wp);
        const float4 wb = *reinterpret_cast<const float4*>(wp + 4);
        const f16x8 a = {(f16)wa.x, (f16)wa.y, (f16)wa.z, (f16)wa.w,
                         (f16)wb.x, (f16)wb.y, (f16)wb.z, (f16)wb.w};
#pragma unroll
        for (int nt = 0; nt < 4; ++nt) {
            const f16x8 bf = *reinterpret_cast<const f16x8*>(
                &Ot[((size_t)(b * NT + n0 + nt * 16 + lm)) * CH + ks * 32 + lg * 8]);
            acc[nt] = MFMA16(a, bf, acc[nt]);
        }
    }

    const int ob = o0 + w * 16 + lg * 4;
    const float4 bias4 = *reinterpret_cast<const float4*>(&bo[ob]);
    const float bb[4] = {bias4.x, bias4.y, bias4.z, bias4.w};
#pragma unroll
    for (int nt = 0; nt < 4; ++nt) {
        const int n = n0 + nt * 16 + lm;
#pragma unroll
        for (int r = 0; r < 4; ++r)
            Y[((size_t)(b * CH + ob + r)) * NT + n] = acc[nt][r] + bb[r];
    }
}

// ---------------------------------------------------------------------------
extern "C" void kernel_launch(void* const* d_in, const int* in_sizes, int n_in,
                              void* d_out, int out_size, void* d_ws, size_t ws_size,
                              hipStream_t stream) {
    (void)in_sizes; (void)n_in; (void)out_size; (void)ws_size;
    const float* x  = (const float*)d_in[0];
    const float* wk = (const float*)d_in[1];
    const float* bk = (const float*)d_in[2];
    const float* wq = (const float*)d_in[3];
    const float* bq = (const float*)d_in[4];
    const float* wv = (const float*)d_in[5];
    const float* bv = (const float*)d_in[6];
    const float* wo = (const float*)d_in[7];
    const float* bo = (const float*)d_in[8];
    float* out = (float*)d_out;

    const size_t SZ = (size_t)NB * NT * CH;
    f16* Kt = (f16*)d_ws;
    f16* Qt = Kt + SZ;
    f16* Vg = Qt + SZ;
    f16* Ot = Vg + SZ;

    proj_qkv_mfma<<<dim3(36, 3, 4), 256, 0, stream>>>(
        wk, bk, wq, bq, wv, bv, x, Kt, Qt, Vg);

    // ---- ablation probes (outputs overwritten by the final V0 pass) -----
    attn_abl<1><<<dim3(576), 256, 0, stream>>>(Kt, Qt, Vg, Ot);  // no-stage
    attn_abl<2><<<dim3(576), 256, 0, stream>>>(Kt, Qt, Vg, Ot);  // no-exp
    attn_abl<3><<<dim3(576), 256, 0, stream>>>(Kt, Qt, Vg, Ot);  // skeleton
    // ---- canonical pass (correct output) --------------------------------
    attn_abl<0><<<dim3(576), 256, 0, stream>>>(Kt, Qt, Vg, Ot);

    out_gemm_mfma<<<dim3(36, 4, 4), 256, 0, stream>>>(wo, bo, Ot, out);
}

// Round 16
// 153.052 us; speedup vs baseline: 1.4601x; 1.4601x over previous
//
#include <hip/hip_runtime.h>
#include <math.h>

#define NB 4
#define CH 256
#define NHEADS 4
#define HC 64
#define NT 2304    // 48*48
#define KSEG 1152  // keys per segment (split-K x2)
#define NSEG 18    // 64-key chunks per segment

typedef _Float16 f16;
typedef _Float16 f16x4 __attribute__((ext_vector_type(4)));
typedef _Float16 f16x8 __attribute__((ext_vector_type(8)));
typedef float f32x4 __attribute__((ext_vector_type(4)));
typedef float f32x16 __attribute__((ext_vector_type(16)));

#define MFMA16(a, b, c) __builtin_amdgcn_mfma_f32_16x16x32_f16(a, b, c, 0, 0, 0)
#define MFMA32(a, b, c) __builtin_amdgcn_mfma_f32_32x32x16_f16(a, b, c, 0, 0, 0)

__device__ __forceinline__ unsigned pkh(float a, float b) {
    auto r = __builtin_amdgcn_cvt_pkrtz(a, b);   // __fp16 ext_vector(2)
    return __builtin_bit_cast(unsigned, r);
}
__device__ __forceinline__ void swap32(unsigned& a, unsigned& b) {
    asm volatile("v_permlane32_swap_b32 %0, %1" : "+v"(a), "+v"(b));
}

// ---------------------------------------------------------------------------
// Fused K/Q/V projection reading x directly (unchanged from R9-R13).
// ---------------------------------------------------------------------------
__global__ __launch_bounds__(256) void proj_qkv_mfma(
    const float* __restrict__ wk, const float* __restrict__ bk,
    const float* __restrict__ wq, const float* __restrict__ bq,
    const float* __restrict__ wv, const float* __restrict__ bv,
    const float* __restrict__ X,
    f16* __restrict__ Kt, f16* __restrict__ Qt, f16* __restrict__ Vg)
{
    const int t = threadIdx.x, l = t & 63, w = t >> 6;
    const int lm = l & 15, lg = l >> 4;
    const int n0 = blockIdx.x * 64;
    const int sel = blockIdx.y;
    const int b = blockIdx.z;

    const float* W  = sel == 0 ? wk : (sel == 1 ? wq : wv);
    const float* Bi = sel == 0 ? bk : (sel == 1 ? bq : bv);

    f32x4 acc[4][4] = {};

#pragma unroll 2
    for (int ks = 0; ks < 8; ++ks) {
        f16x8 bf[4];
#pragma unroll
        for (int nt = 0; nt < 4; ++nt) {
            const float* xp = &X[((size_t)b * CH + ks * 32 + lg * 8) * NT
                                 + n0 + nt * 16 + lm];
            f16x8 v;
#pragma unroll
            for (int j = 0; j < 8; ++j) v[j] = (f16)xp[(size_t)j * NT];
            bf[nt] = v;
        }
#pragma unroll
        for (int h = 0; h < 4; ++h) {
            const float* wp = &W[(size_t)(h * 64 + w * 16 + lm) * CH + ks * 32 + lg * 8];
            const float4 wa = *reinterpret_cast<const float4*>(wp);
            const float4 wb = *reinterpret_cast<const float4*>(wp + 4);
            const f16x8 a = {(f16)wa.x, (f16)wa.y, (f16)wa.z, (f16)wa.w,
                             (f16)wb.x, (f16)wb.y, (f16)wb.z, (f16)wb.w};
#pragma unroll
            for (int nt = 0; nt < 4; ++nt)
                acc[h][nt] = MFMA16(a, bf[nt], acc[h][nt]);
        }
    }

    const int c_base = w * 16 + lg * 4;
#pragma unroll
    for (int h = 0; h < 4; ++h) {
        const float4 b4 = *reinterpret_cast<const float4*>(&Bi[h * 64 + c_base]);
        const float bb[4] = {b4.x, b4.y, b4.z, b4.w};
        if (sel < 2) {
            f16* Out = sel == 0 ? Kt : Qt;
#pragma unroll
            for (int nt = 0; nt < 4; ++nt) {
                const int n = n0 + nt * 16 + lm;
                f16x4 o = {(f16)(acc[h][nt][0] + bb[0]), (f16)(acc[h][nt][1] + bb[1]),
                           (f16)(acc[h][nt][2] + bb[2]), (f16)(acc[h][nt][3] + bb[3])};
                *reinterpret_cast<f16x4*>(
                    &Out[((size_t)((b * NHEADS + h) * NT + n)) * HC + c_base]) = o;
            }
        } else {
#pragma unroll
            for (int nt = 0; nt < 4; ++nt) {
                const int n = n0 + nt * 16 + lm;
#pragma unroll
                for (int r = 0; r < 4; ++r)
                    Vg[((size_t)((b * NHEADS + h) * HC + c_base + r)) * NT + n] =
                        (f16)(acc[h][nt][r] + bb[r]);
            }
        }
    }
}

// ---------------------------------------------------------------------------
// Flash attention, ZERO-BARRIER / ZERO-LDS main loop.  K/V read DIRECTLY
// from L2 into registers (coalesced 32-row x 32B per instr); K manually
// double-buffered (even/odd unroll -> static reg rename); V issued before
// softmax so its latency hides under QK+exp.  No s_barrier in the loop ->
// no vmcnt(0) drains; waves free-run and de-phase (fixes the lockstep that
// made stage/softmax/MFMA phases serial per R13's ablation).
// Split-K x2, 32 q/wave, in-reg P (pkrtz+permlane), defer-max THR=8.
// Merge epilogue (only barriers in the kernel) as R9.
// grid 576, block 256.  XCD decode: xcd = bid&7 owns 2 (b,h) pairs.
// ---------------------------------------------------------------------------
__global__ __launch_bounds__(256) void attn_nobar(
    const f16* __restrict__ Kt, const f16* __restrict__ Qt,
    const f16* __restrict__ Vg, f16* __restrict__ Ot)
{
    __shared__ float Part[2][64][64];   // 32KB, used only in epilogue
    __shared__ float Ml[2][64], Ll[2][64];

    const int t = threadIdx.x, l = t & 63, w = t >> 6;
    const int col = l & 31, hi = l >> 5;
    const int qh = w & 1, sg = w >> 1;

    const int bid = blockIdx.x;
    const int xcd = bid & 7, idx = bid >> 3;
    const int bh  = 2 * xcd + (idx >= 36 ? 1 : 0);
    const int qt  = idx >= 36 ? idx - 36 : idx;
    const int b = bh >> 2, h = bh & 3;
    const int m0 = qt * 64;

    const size_t bhs = (size_t)(b * NHEADS + h);
    const f16* Kb = Kt + bhs * NT * HC;   // [n][64c]
    const f16* Qb = Qt + bhs * NT * HC;
    const f16* Vb = Vg + bhs * HC * NT;   // [c][n]

    const int q = m0 + qh * 32 + col;
    f16x8 qf[4];
#pragma unroll
    for (int cs = 0; cs < 4; ++cs)
        qf[cs] = *reinterpret_cast<const f16x8*>(
            &Qb[(size_t)q * HC + cs * 16 + hi * 8]);

    const f32x16 Z16 = {0,0,0,0,0,0,0,0,0,0,0,0,0,0,0,0};
    f32x16 acc0 = Z16, acc1 = Z16;
    float m_run = -3.0e38f, l_run = 0.0f;

    const int kbase = sg * KSEG;

    // K A-frags for one 64-key chunk: kf[cs] keys col, kf[4+cs] keys 32+col
    auto loadK = [&](int kc, f16x8 (&kf)[8]) {
#pragma unroll
        for (int cs = 0; cs < 4; ++cs) {
            kf[cs] = *reinterpret_cast<const f16x8*>(
                &Kb[(size_t)(kc + col) * HC + cs * 16 + hi * 8]);
            kf[4 + cs] = *reinterpret_cast<const f16x8*>(
                &Kb[(size_t)(kc + 32 + col) * HC + cs * 16 + hi * 8]);
        }
    };
    auto loadV = [&](int kc, f16x8 (&vf)[8]) {
#pragma unroll
        for (int kk = 0; kk < 4; ++kk) {
            vf[kk] = *reinterpret_cast<const f16x8*>(
                &Vb[(size_t)col * NT + kc + kk * 16 + hi * 8]);
            vf[4 + kk] = *reinterpret_cast<const f16x8*>(
                &Vb[(size_t)(32 + col) * NT + kc + kk * 16 + hi * 8]);
        }
    };

    // process one chunk whose K-frags are already in kf
    auto process = [&](int kc, const f16x8 (&kf)[8]) {
        f16x8 vf[8];
        loadV(kc, vf);                      // issued first; used after softmax

        f32x16 s0 = Z16, s1 = Z16;
#pragma unroll
        for (int cs = 0; cs < 4; ++cs) {
            s0 = MFMA32(kf[cs],     qf[cs], s0);
            s1 = MFMA32(kf[4 + cs], qf[cs], s1);
        }

        float m8[8];
#pragma unroll
        for (int j = 0; j < 8; ++j)
            m8[j] = fmaxf(fmaxf(s0[2 * j], s0[2 * j + 1]),
                          fmaxf(s1[2 * j], s1[2 * j + 1]));
        float cm = fmaxf(fmaxf(fmaxf(m8[0], m8[1]), fmaxf(m8[2], m8[3])),
                         fmaxf(fmaxf(m8[4], m8[5]), fmaxf(m8[6], m8[7])));
        cm = fmaxf(cm, __shfl_xor(cm, 32));
        if (!__all(cm <= m_run + 8.0f)) {   // defer-max, THR=8
            const float mN = fmaxf(m_run, cm);
            const float fac = __expf(m_run - mN);
#pragma unroll
            for (int r = 0; r < 16; ++r) { acc0[r] *= fac; acc1[r] *= fac; }
            l_run *= fac;
            m_run = mN;
        }
        float p0[16], p1[16];
        float ps0 = 0.f, ps1 = 0.f, ps2 = 0.f, ps3 = 0.f;
#pragma unroll
        for (int r = 0; r < 4; ++r) {
            p0[r]      = __expf(s0[r]      - m_run); ps0 += p0[r];
            p0[r + 4]  = __expf(s0[r + 4]  - m_run); ps1 += p0[r + 4];
            p0[r + 8]  = __expf(s0[r + 8]  - m_run); ps2 += p0[r + 8];
            p0[r + 12] = __expf(s0[r + 12] - m_run); ps3 += p0[r + 12];
            p1[r]      = __expf(s1[r]      - m_run); ps0 += p1[r];
            p1[r + 4]  = __expf(s1[r + 4]  - m_run); ps1 += p1[r + 4];
            p1[r + 8]  = __expf(s1[r + 8]  - m_run); ps2 += p1[r + 8];
            p1[r + 12] = __expf(s1[r + 12] - m_run); ps3 += p1[r + 12];
        }
        l_run += (ps0 + ps1) + (ps2 + ps3);

        unsigned a0[8], a1[8];
#pragma unroll
        for (int j = 0; j < 8; ++j) {
            a0[j] = pkh(p0[2 * j], p0[2 * j + 1]);
            a1[j] = pkh(p1[2 * j], p1[2 * j + 1]);
        }
        swap32(a0[0], a0[2]); swap32(a0[1], a0[3]);
        swap32(a0[4], a0[6]); swap32(a0[5], a0[7]);
        swap32(a1[0], a1[2]); swap32(a1[1], a1[3]);
        swap32(a1[4], a1[6]); swap32(a1[5], a1[7]);
        union BU { unsigned u[4]; f16x8 v; };
        BU fr[4];
        fr[0].u[0] = a0[0]; fr[0].u[1] = a0[1]; fr[0].u[2] = a0[2]; fr[0].u[3] = a0[3];
        fr[1].u[0] = a0[4]; fr[1].u[1] = a0[5]; fr[1].u[2] = a0[6]; fr[1].u[3] = a0[7];
        fr[2].u[0] = a1[0]; fr[2].u[1] = a1[1]; fr[2].u[2] = a1[2]; fr[2].u[3] = a1[3];
        fr[3].u[0] = a1[4]; fr[3].u[1] = a1[5]; fr[3].u[2] = a1[6]; fr[3].u[3] = a1[7];

#pragma unroll
        for (int kk = 0; kk < 4; ++kk) {
            acc0 = MFMA32(vf[kk],     fr[kk].v, acc0);
            acc1 = MFMA32(vf[4 + kk], fr[kk].v, acc1);
        }
    };

    // ---- zero-barrier main loop: K double-buffered even/odd -------------
    f16x8 kf0[8], kf1[8];
    loadK(kbase, kf0);
    for (int ii = 0; ii < NSEG / 2; ++ii) {
        const int kc0 = kbase + ii * 128;
        loadK(kc0 + 64, kf1);               // prefetch odd chunk
        process(kc0, kf0);
        if (ii + 1 < NSEG / 2) loadK(kc0 + 128, kf0);   // prefetch next even
        process(kc0 + 64, kf1);
    }

    // ---- publish + 2-way merge (only barriers in the kernel) ------------
    const float l_full = l_run + __shfl_xor(l_run, 32);
    if (hi == 0) {
        Ml[sg][qh * 32 + col] = m_run;
        Ll[sg][qh * 32 + col] = l_full;
    }
    {
        float* row = &Part[sg][qh * 32 + col][0];
#pragma unroll
        for (int rq = 0; rq < 4; ++rq) {
            const int c0 = rq * 8 + hi * 4;
            f32x4 o0 = {acc0[rq * 4 + 0], acc0[rq * 4 + 1],
                        acc0[rq * 4 + 2], acc0[rq * 4 + 3]};
            f32x4 o1 = {acc1[rq * 4 + 0], acc1[rq * 4 + 1],
                        acc1[rq * 4 + 2], acc1[rq * 4 + 3]};
            *reinterpret_cast<f32x4*>(row + c0) = o0;
            *reinterpret_cast<f32x4*>(row + 32 + c0) = o1;
        }
    }
    __syncthreads();
    {
        const int qq = t >> 2, c0 = (t & 3) * 16;
        const float mA = Ml[0][qq], mB = Ml[1][qq];
        const float M = fmaxf(mA, mB);
        const float wA = __expf(mA - M), wB = __expf(mB - M);
        const float inv = 1.0f / (wA * Ll[0][qq] + wB * Ll[1][qq]);
        const float* r0 = &Part[0][qq][0];
        const float* r1 = &Part[1][qq][0];
        f16* dst = &Ot[((size_t)(b * NT + m0 + qq)) * CH + h * HC + c0];
#pragma unroll
        for (int j = 0; j < 16; j += 4) {
            const f32x4 aA = *reinterpret_cast<const f32x4*>(r0 + c0 + j);
            const f32x4 aB = *reinterpret_cast<const f32x4*>(r1 + c0 + j);
            f16x4 o = {(f16)((wA * aA[0] + wB * aB[0]) * inv),
                       (f16)((wA * aA[1] + wB * aB[1]) * inv),
                       (f16)((wA * aA[2] + wB * aB[2]) * inv),
                       (f16)((wA * aA[3] + wB * aB[3]) * inv)};
            *reinterpret_cast<f16x4*>(dst + j) = o;
        }
    }
}

// ---------------------------------------------------------------------------
// Final conv1x1 (unchanged). grid (36, 4, 4).
// ---------------------------------------------------------------------------
__global__ __launch_bounds__(256) void out_gemm_mfma(
    const float* __restrict__ wo, const float* __restrict__ bo,
    const f16* __restrict__ Ot, float* __restrict__ Y)
{
    const int t = threadIdx.x, l = t & 63, w = t >> 6;
    const int lm = l & 15, lg = l >> 4;
    const int n0 = blockIdx.x * 64;
    const int o0 = blockIdx.y * 64;
    const int b = blockIdx.z;

    f32x4 acc[4] = {{0.f,0.f,0.f,0.f},{0.f,0.f,0.f,0.f},
                    {0.f,0.f,0.f,0.f},{0.f,0.f,0.f,0.f}};
    const int o_row = o0 + w * 16 + lm;

#pragma unroll
    for (int ks = 0; ks < 8; ++ks) {
        const float* wp = &wo[(size_t)o_row * CH + ks * 32 + lg * 8];
        const float4 wa = *reinterpret_cast<const float4*>(wp);
        const float4 wb = *reinterpret_cast<const float4*>(wp + 4);
        const f16x8 a = {(f16)wa.x, (f16)wa.y, (f16)wa.z, (f16)wa.w,
                         (f16)wb.x, (f16)wb.y, (f16)wb.z, (f16)wb.w};
#pragma unroll
        for (int nt = 0; nt < 4; ++nt) {
            const f16x8 bf = *reinterpret_cast<const f16x8*>(
                &Ot[((size_t)(b * NT + n0 + nt * 16 + lm)) * CH + ks * 32 + lg * 8]);
            acc[nt] = MFMA16(a, bf, acc[nt]);
        }
    }

    const int ob = o0 + w * 16 + lg * 4;
    const float4 bias4 = *reinterpret_cast<const float4*>(&bo[ob]);
    const float bb[4] = {bias4.x, bias4.y, bias4.z, bias4.w};
#pragma unroll
    for (int nt = 0; nt < 4; ++nt) {
        const int n = n0 + nt * 16 + lm;
#pragma unroll
        for (int r = 0; r < 4; ++r)
            Y[((size_t)(b * CH + ob + r)) * NT + n] = acc[nt][r] + bb[r];
    }
}

// ---------------------------------------------------------------------------
extern "C" void kernel_launch(void* const* d_in, const int* in_sizes, int n_in,
                              void* d_out, int out_size, void* d_ws, size_t ws_size,
                              hipStream_t stream) {
    (void)in_sizes; (void)n_in; (void)out_size; (void)ws_size;
    const float* x  = (const float*)d_in[0];
    const float* wk = (const float*)d_in[1];
    const float* bk = (const float*)d_in[2];
    const float* wq = (const float*)d_in[3];
    const float* bq = (const float*)d_in[4];
    const float* wv = (const float*)d_in[5];
    const float* bv = (const float*)d_in[6];
    const float* wo = (const float*)d_in[7];
    const float* bo = (const float*)d_in[8];
    float* out = (float*)d_out;

    const size_t SZ = (size_t)NB * NT * CH;
    f16* Kt = (f16*)d_ws;
    f16* Qt = Kt + SZ;
    f16* Vg = Qt + SZ;
    f16* Ot = Vg + SZ;

    proj_qkv_mfma<<<dim3(36, 3, 4), 256, 0, stream>>>(
        wk, bk, wq, bq, wv, bv, x, Kt, Qt, Vg);
    attn_nobar<<<dim3(576), 256, 0, stream>>>(Kt, Qt, Vg, Ot);
    out_gemm_mfma<<<dim3(36, 4, 4), 256, 0, stream>>>(wo, bo, Ot, out);
}

// Round 18
// 104.731 us; speedup vs baseline: 2.1337x; 1.4614x over previous
//
#include <hip/hip_runtime.h>
#include <math.h>

#define NB 4
#define CH 256
#define NHEADS 4
#define HC 64
#define NT 2304    // 48*48
#define KSEG 576   // keys per segment (split-K x4)
#define NSEG 9     // 64-key chunks per segment

typedef _Float16 f16;
typedef _Float16 f16x4 __attribute__((ext_vector_type(4)));
typedef _Float16 f16x8 __attribute__((ext_vector_type(8)));
typedef float f32x4 __attribute__((ext_vector_type(4)));
typedef float f32x16 __attribute__((ext_vector_type(16)));

#define MFMA16(a, b, c) __builtin_amdgcn_mfma_f32_16x16x32_f16(a, b, c, 0, 0, 0)
#define MFMA32(a, b, c) __builtin_amdgcn_mfma_f32_32x32x16_f16(a, b, c, 0, 0, 0)

__device__ __forceinline__ void gload_lds16(const void* g, void* l) {
    __builtin_amdgcn_global_load_lds(
        (const __attribute__((address_space(1))) unsigned int*)g,
        (__attribute__((address_space(3))) unsigned int*)l, 16, 0, 0);
}

__device__ __forceinline__ unsigned pkh(float a, float b) {
    auto r = __builtin_amdgcn_cvt_pkrtz(a, b);   // __fp16 ext_vector(2)
    return __builtin_bit_cast(unsigned, r);
}
__device__ __forceinline__ void swap32(unsigned& a, unsigned& b) {
    asm volatile("v_permlane32_swap_b32 %0, %1" : "+v"(a), "+v"(b));
}

// ---------------------------------------------------------------------------
// Fused K/Q/V projection v2: x-tile staged ONCE per block, TRANSPOSED in LDS.
//   - x read as float4 (16 lanes x 16B = 256B/row, fully coalesced)
//   - B-frag = ONE ds_read_b128 from T[n][c]   (was: 8 scalar stride-9KB loads)
//   - V output via LDS transpose buffer -> full-128B f16x8 stores
//     (was: 64 scalar 2B stores per thread)
// grid (36, 3, 4) = (ntile64, sel, b), block 256 = 4 waves.
// Outputs: K,Q as [b][h][n][64c]; V as [b][h][64c][n].  (layouts unchanged)
// ---------------------------------------------------------------------------
__global__ __launch_bounds__(256) void proj_qkv_v2(
    const float* __restrict__ wk, const float* __restrict__ bk,
    const float* __restrict__ wq, const float* __restrict__ bq,
    const float* __restrict__ wv, const float* __restrict__ bv,
    const float* __restrict__ X,
    f16* __restrict__ Kt, f16* __restrict__ Qt, f16* __restrict__ Vg)
{
    // union: x-tile T[64][264] f16 = 33792 B;  V-buffer Vt[256][80] f16 = 40960 B
    __shared__ __align__(16) char SMEM[40960];
    f16 (*T)[264]  = reinterpret_cast<f16(*)[264]>(SMEM);
    f16 (*Vt)[80]  = reinterpret_cast<f16(*)[80]>(SMEM);

    const int t = threadIdx.x, l = t & 63, w = t >> 6;
    const int lm = l & 15, lg = l >> 4;
    const int n0 = blockIdx.x * 64;
    const int sel = blockIdx.y;
    const int b = blockIdx.z;

    const float* W  = sel == 0 ? wk : (sel == 1 ? wq : wv);
    const float* Bi = sel == 0 ? bk : (sel == 1 ? bq : bv);

    // ---- stage x[b][0..255][n0..n0+64) transposed -> T[n][c] ------------
    {
        const int cq = t >> 4;            // 0..15: c within group of 16
        const int nq = (t & 15) * 4;      // 0,4,...,60
#pragma unroll
        for (int p = 0; p < 16; ++p) {
            const int c = p * 16 + cq;
            const float4 v = *reinterpret_cast<const float4*>(
                &X[((size_t)b * CH + c) * NT + n0 + nq]);
            T[nq + 0][c] = (f16)v.x;
            T[nq + 1][c] = (f16)v.y;
            T[nq + 2][c] = (f16)v.z;
            T[nq + 3][c] = (f16)v.w;
        }
    }
    __syncthreads();

    f32x4 acc[4][4] = {};   // [h][nt]

#pragma unroll 2
    for (int ks = 0; ks < 8; ++ks) {
        f16x8 bf[4];
#pragma unroll
        for (int nt = 0; nt < 4; ++nt)
            bf[nt] = *reinterpret_cast<const f16x8*>(
                &T[nt * 16 + lm][ks * 32 + lg * 8]);
#pragma unroll
        for (int h = 0; h < 4; ++h) {
            const float* wp = &W[(size_t)(h * 64 + w * 16 + lm) * CH + ks * 32 + lg * 8];
            const float4 wa = *reinterpret_cast<const float4*>(wp);
            const float4 wb = *reinterpret_cast<const float4*>(wp + 4);
            const f16x8 a = {(f16)wa.x, (f16)wa.y, (f16)wa.z, (f16)wa.w,
                             (f16)wb.x, (f16)wb.y, (f16)wb.z, (f16)wb.w};
#pragma unroll
            for (int nt = 0; nt < 4; ++nt)
                acc[h][nt] = MFMA16(a, bf[nt], acc[h][nt]);
        }
    }

    const int c_base = w * 16 + lg * 4;
    if (sel < 2) {
        f16* Out = sel == 0 ? Kt : Qt;
#pragma unroll
        for (int h = 0; h < 4; ++h) {
            const float4 b4 = *reinterpret_cast<const float4*>(&Bi[h * 64 + c_base]);
            const float bb[4] = {b4.x, b4.y, b4.z, b4.w};
#pragma unroll
            for (int nt = 0; nt < 4; ++nt) {
                const int n = n0 + nt * 16 + lm;
                f16x4 o = {(f16)(acc[h][nt][0] + bb[0]), (f16)(acc[h][nt][1] + bb[1]),
                           (f16)(acc[h][nt][2] + bb[2]), (f16)(acc[h][nt][3] + bb[3])};
                *reinterpret_cast<f16x4*>(
                    &Out[((size_t)((b * NHEADS + h) * NT + n)) * HC + c_base]) = o;
            }
        }
    } else {
        // ---- V: acc -> LDS transpose buffer -> coalesced 128B stores ----
        __syncthreads();   // x-tile dead; reuse SMEM as Vt[256][80]
#pragma unroll
        for (int h = 0; h < 4; ++h)
#pragma unroll
            for (int nt = 0; nt < 4; ++nt)
#pragma unroll
                for (int r = 0; r < 4; ++r)
                    Vt[h * 64 + c_base + r][nt * 16 + lm] = (f16)acc[h][nt][r];
        __syncthreads();
#pragma unroll
        for (int p = 0; p < 8; ++p) {
            const int c  = p * 32 + (t >> 3);   // 0..255 (h*64 + ch)
            const int nn = (t & 7) * 8;
            const float bb = Bi[c];
            const f16x8 vv = *reinterpret_cast<const f16x8*>(&Vt[c][nn]);
            f16x8 o;
#pragma unroll
            for (int j = 0; j < 8; ++j) o[j] = (f16)((float)vv[j] + bb);
            *reinterpret_cast<f16x8*>(
                &Vg[((size_t)((b * NHEADS + (c >> 6)) * HC + (c & 63))) * NT
                    + n0 + nn]) = o;
        }
    }
}

// ---------------------------------------------------------------------------
// Flash attention, 32x32x16 MFMA, SPLIT-K x4, 8-wave blocks (512 thr).
// (R11 verbatim — best measured 64.5 µs.)  grid 576, block 512.
// ---------------------------------------------------------------------------
__global__ __launch_bounds__(512, 4) void attn_split4(
    const f16* __restrict__ Kt, const f16* __restrict__ Qt,
    const f16* __restrict__ Vg, f16* __restrict__ Ot)
{
    __shared__ f16 SM[4][2][4096];   // [seg][K/V][64 rows x 64c] = 64KB
    __shared__ float Ml[4][64], Ll[4][64];

    const int t = threadIdx.x, l = t & 63, w = t >> 6;
    const int col = l & 31, hi = l >> 5;
    const int qh = w & 1, sg = w >> 1;   // query half (0..1), key segment (0..3)

    const int bid = blockIdx.x;
    const int xcd = bid & 7, idx = bid >> 3;
    const int bh  = 2 * xcd + (idx >= 36 ? 1 : 0);
    const int qt  = idx >= 36 ? idx - 36 : idx;
    const int b = bh >> 2, h = bh & 3;
    const int m0 = qt * 64;

    const size_t bhs = (size_t)(b * NHEADS + h);
    const f16* Kb = Kt + bhs * NT * HC;   // [n][64c] rows of 128 B
    const f16* Qb = Qt + bhs * NT * HC;
    const f16* Vb = Vg + bhs * HC * NT;   // [c][n]

    const int srow = l >> 3, su = l & 7, sx = su ^ srow;

    const int q = m0 + qh * 32 + col;
    f16x8 qf[4];
#pragma unroll
    for (int cs = 0; cs < 4; ++cs)
        qf[cs] = *reinterpret_cast<const f16x8*>(
            &Qb[(size_t)q * HC + cs * 16 + hi * 8]);

    const f32x16 Z16 = {0,0,0,0,0,0,0,0,0,0,0,0,0,0,0,0};
    f32x16 acc0 = Z16, acc1 = Z16;
    float m_run = -3.0e38f, l_run = 0.0f;

    const int kbase = sg * KSEG;

    auto stage = [&](int kc) {
        if (qh == 0) {
            const char* src = (const char*)(Kb + (size_t)kc * HC);
            char* dst = (char*)&SM[sg][0][0];
#pragma unroll
            for (int g = 0; g < 8; ++g)
                gload_lds16(src + (size_t)(g * 8 + srow) * 128 + (sx << 4),
                            dst + g * 1024);
        } else {
            const char* src = (const char*)Vb + (size_t)kc * 2;
            char* dst = (char*)&SM[sg][1][0];
#pragma unroll
            for (int g = 0; g < 8; ++g)
                gload_lds16(src + (size_t)(g * 8 + srow) * (NT * 2) + (sx << 4),
                            dst + g * 1024);
        }
    };

    auto rd = [&](const f16* base, int row, int u) -> f16x8 {
        return *reinterpret_cast<const f16x8*>(
            base + row * 64 + ((u ^ (row & 7)) << 3));
    };

    stage(kbase);
    __syncthreads();

    for (int i = 0; i < NSEG; ++i) {
        const f16* Kc = &SM[sg][0][0];
        const f16* Vc = &SM[sg][1][0];

        f32x16 s0 = Z16, s1 = Z16;
#pragma unroll
        for (int cs = 0; cs < 4; ++cs) {
            const f16x8 k0 = rd(Kc, col,      cs * 2 + hi);
            const f16x8 k1 = rd(Kc, 32 + col, cs * 2 + hi);
            s0 = MFMA32(k0, qf[cs], s0);
            s1 = MFMA32(k1, qf[cs], s1);
        }

        float m8[8];
#pragma unroll
        for (int j = 0; j < 8; ++j)
            m8[j] = fmaxf(fmaxf(s0[2 * j], s0[2 * j + 1]),
                          fmaxf(s1[2 * j], s1[2 * j + 1]));
        float cm = fmaxf(fmaxf(fmaxf(m8[0], m8[1]), fmaxf(m8[2], m8[3])),
                         fmaxf(fmaxf(m8[4], m8[5]), fmaxf(m8[6], m8[7])));
        cm = fmaxf(cm, __shfl_xor(cm, 32));
        if (!__all(cm <= m_run + 8.0f)) {     // defer-max, THR=8
            const float mN = fmaxf(m_run, cm);
            const float fac = __expf(m_run - mN);
#pragma unroll
            for (int r = 0; r < 16; ++r) { acc0[r] *= fac; acc1[r] *= fac; }
            l_run *= fac;
            m_run = mN;
        }
        float p0[16], p1[16];
        float ps0 = 0.f, ps1 = 0.f, ps2 = 0.f, ps3 = 0.f;
#pragma unroll
        for (int r = 0; r < 4; ++r) {
            p0[r]      = __expf(s0[r]      - m_run); ps0 += p0[r];
            p0[r + 4]  = __expf(s0[r + 4]  - m_run); ps1 += p0[r + 4];
            p0[r + 8]  = __expf(s0[r + 8]  - m_run); ps2 += p0[r + 8];
            p0[r + 12] = __expf(s0[r + 12] - m_run); ps3 += p0[r + 12];
            p1[r]      = __expf(s1[r]      - m_run); ps0 += p1[r];
            p1[r + 4]  = __expf(s1[r + 4]  - m_run); ps1 += p1[r + 4];
            p1[r + 8]  = __expf(s1[r + 8]  - m_run); ps2 += p1[r + 8];
            p1[r + 12] = __expf(s1[r + 12] - m_run); ps3 += p1[r + 12];
        }
        l_run += (ps0 + ps1) + (ps2 + ps3);

        unsigned a0[8], a1[8];
#pragma unroll
        for (int j = 0; j < 8; ++j) {
            a0[j] = pkh(p0[2 * j], p0[2 * j + 1]);
            a1[j] = pkh(p1[2 * j], p1[2 * j + 1]);
        }
        swap32(a0[0], a0[2]); swap32(a0[1], a0[3]);   // keys 0-15
        swap32(a0[4], a0[6]); swap32(a0[5], a0[7]);   // keys 16-31
        swap32(a1[0], a1[2]); swap32(a1[1], a1[3]);   // keys 32-47
        swap32(a1[4], a1[6]); swap32(a1[5], a1[7]);   // keys 48-63
        union BU { unsigned u[4]; f16x8 v; };
        BU fr[4];
        fr[0].u[0] = a0[0]; fr[0].u[1] = a0[1]; fr[0].u[2] = a0[2]; fr[0].u[3] = a0[3];
        fr[1].u[0] = a0[4]; fr[1].u[1] = a0[5]; fr[1].u[2] = a0[6]; fr[1].u[3] = a0[7];
        fr[2].u[0] = a1[0]; fr[2].u[1] = a1[1]; fr[2].u[2] = a1[2]; fr[2].u[3] = a1[3];
        fr[3].u[0] = a1[4]; fr[3].u[1] = a1[5]; fr[3].u[2] = a1[6]; fr[3].u[3] = a1[7];

#pragma unroll
        for (int kk = 0; kk < 4; ++kk) {
            const f16x8 v0 = rd(Vc, col,      kk * 2 + hi);
            const f16x8 v1 = rd(Vc, 32 + col, kk * 2 + hi);
            acc0 = MFMA32(v0, fr[kk].v, acc0);
            acc1 = MFMA32(v1, fr[kk].v, acc1);
        }

        __syncthreads();
        if (i + 1 < NSEG) {
            stage(kbase + (i + 1) * 64);
            __syncthreads();
        }
    }

    // ---- publish segment partials (reuse SM as f32 Part[4*64][64]) ------
    float* Part = (float*)&SM[0][0][0];
    const float l_full = l_run + __shfl_xor(l_run, 32);
    __syncthreads();
    if (hi == 0) {
        Ml[sg][qh * 32 + col] = m_run;
        Ll[sg][qh * 32 + col] = l_full;
    }
    {
        float* row = Part + ((size_t)(sg * 64 + qh * 32 + col)) * 64;
#pragma unroll
        for (int rq = 0; rq < 4; ++rq) {
            const int c0 = rq * 8 + hi * 4;
            f32x4 o0 = {acc0[rq * 4 + 0], acc0[rq * 4 + 1],
                        acc0[rq * 4 + 2], acc0[rq * 4 + 3]};
            f32x4 o1 = {acc1[rq * 4 + 0], acc1[rq * 4 + 1],
                        acc1[rq * 4 + 2], acc1[rq * 4 + 3]};
            *reinterpret_cast<f32x4*>(row + c0) = o0;
            *reinterpret_cast<f32x4*>(row + 32 + c0) = o1;
        }
    }
    __syncthreads();

    {
        const int qq = t >> 3, c0 = (t & 7) * 8;
        const float m0_ = Ml[0][qq], m1_ = Ml[1][qq];
        const float m2_ = Ml[2][qq], m3_ = Ml[3][qq];
        const float M = fmaxf(fmaxf(m0_, m1_), fmaxf(m2_, m3_));
        const float w0 = __expf(m0_ - M), w1 = __expf(m1_ - M);
        const float w2 = __expf(m2_ - M), w3 = __expf(m3_ - M);
        const float inv = 1.0f / (w0 * Ll[0][qq] + w1 * Ll[1][qq]
                                + w2 * Ll[2][qq] + w3 * Ll[3][qq]);
        const float* r0 = Part + (size_t)(0 * 64 + qq) * 64 + c0;
        const float* r1 = Part + (size_t)(1 * 64 + qq) * 64 + c0;
        const float* r2 = Part + (size_t)(2 * 64 + qq) * 64 + c0;
        const float* r3 = Part + (size_t)(3 * 64 + qq) * 64 + c0;
        f16x8 o;
#pragma unroll
        for (int j = 0; j < 8; ++j)
            o[j] = (f16)((w0 * r0[j] + w1 * r1[j] + w2 * r2[j] + w3 * r3[j]) * inv);
        *reinterpret_cast<f16x8*>(
            &Ot[((size_t)(b * NT + m0 + qq)) * CH + h * HC + c0]) = o;
    }
}

// ---------------------------------------------------------------------------
// Final conv1x1 (unchanged). grid (36, 4, 4).
// ---------------------------------------------------------------------------
__global__ __launch_bounds__(256) void out_gemm_mfma(
    const float* __restrict__ wo, const float* __restrict__ bo,
    const f16* __restrict__ Ot, float* __restrict__ Y)
{
    const int t = threadIdx.x, l = t & 63, w = t >> 6;
    const int lm = l & 15, lg = l >> 4;
    const int n0 = blockIdx.x * 64;
    const int o0 = blockIdx.y * 64;
    const int b = blockIdx.z;

    f32x4 acc[4] = {{0.f,0.f,0.f,0.f},{0.f,0.f,0.f,0.f},
                    {0.f,0.f,0.f,0.f},{0.f,0.f,0.f,0.f}};
    const int o_row = o0 + w * 16 + lm;

#pragma unroll
    for (int ks = 0; ks < 8; ++ks) {
        const float* wp = &wo[(size_t)o_row * CH + ks * 32 + lg * 8];
        const float4 wa = *reinterpret_cast<const float4*>(wp);
        const float4 wb = *reinterpret_cast<const float4*>(wp + 4);
        const f16x8 a = {(f16)wa.x, (f16)wa.y, (f16)wa.z, (f16)wa.w,
                         (f16)wb.x, (f16)wb.y, (f16)wb.z, (f16)wb.w};
#pragma unroll
        for (int nt = 0; nt < 4; ++nt) {
            const f16x8 bf = *reinterpret_cast<const f16x8*>(
                &Ot[((size_t)(b * NT + n0 + nt * 16 + lm)) * CH + ks * 32 + lg * 8]);
            acc[nt] = MFMA16(a, bf, acc[nt]);
        }
    }

    const int ob = o0 + w * 16 + lg * 4;
    const float4 bias4 = *reinterpret_cast<const float4*>(&bo[ob]);
    const float bb[4] = {bias4.x, bias4.y, bias4.z, bias4.w};
#pragma unroll
    for (int nt = 0; nt < 4; ++nt) {
        const int n = n0 + nt * 16 + lm;
#pragma unroll
        for (int r = 0; r < 4; ++r)
            Y[((size_t)(b * CH + ob + r)) * NT + n] = acc[nt][r] + bb[r];
    }
}

// ---------------------------------------------------------------------------
extern "C" void kernel_launch(void* const* d_in, const int* in_sizes, int n_in,
                              void* d_out, int out_size, void* d_ws, size_t ws_size,
                              hipStream_t stream) {
    (void)in_sizes; (void)n_in; (void)out_size; (void)ws_size;
    const float* x  = (const float*)d_in[0];
    const float* wk = (const float*)d_in[1];
    const float* bk = (const float*)d_in[2];
    const float* wq = (const float*)d_in[3];
    const float* bq = (const float*)d_in[4];
    const float* wv = (const float*)d_in[5];
    const float* bv = (const float*)d_in[6];
    const float* wo = (const float*)d_in[7];
    const float* bo = (const float*)d_in[8];
    float* out = (float*)d_out;

    const size_t SZ = (size_t)NB * NT * CH;   // halves per tensor
    f16* Kt = (f16*)d_ws;        // [b][h][n][c]
    f16* Qt = Kt + SZ;           // [b][h][n][c]
    f16* Vg = Qt + SZ;           // [b][h][c][n]
    f16* Ot = Vg + SZ;           // [b][n][c]

    proj_qkv_v2<<<dim3(36, 3, 4), 256, 0, stream>>>(
        wk, bk, wq, bq, wv, bv, x, Kt, Qt, Vg);
    attn_split4<<<dim3(576), 512, 0, stream>>>(Kt, Qt, Vg, Ot);
    out_gemm_mfma<<<dim3(36, 4, 4), 256, 0, stream>>>(wo, bo, Ot, out);
}

// Round 20
// 100.747 us; speedup vs baseline: 2.2181x; 1.0396x over previous
//
#include <hip/hip_runtime.h>
#include <math.h>

#define NB 4
#define CH 256
#define NHEADS 4
#define HC 64
#define NT 2304    // 48*48
#define KSEG 1152  // keys per segment (2 segments, cross-block)
#define NSEG 18    // 64-key chunks per segment
#define NQT 18     // 128-query tiles

typedef _Float16 f16;
typedef _Float16 f16x4 __attribute__((ext_vector_type(4)));
typedef _Float16 f16x8 __attribute__((ext_vector_type(8)));
typedef float f32x4 __attribute__((ext_vector_type(4)));
typedef float f32x16 __attribute__((ext_vector_type(16)));

#define MFMA16(a, b, c) __builtin_amdgcn_mfma_f32_16x16x32_f16(a, b, c, 0, 0, 0)
#define MFMA32(a, b, c) __builtin_amdgcn_mfma_f32_32x32x16_f16(a, b, c, 0, 0, 0)

__device__ __forceinline__ void gload_lds16(const void* g, void* l) {
    __builtin_amdgcn_global_load_lds(
        (const __attribute__((address_space(1))) unsigned int*)g,
        (__attribute__((address_space(3))) unsigned int*)l, 16, 0, 0);
}

__device__ __forceinline__ unsigned pkh(float a, float b) {
    auto r = __builtin_amdgcn_cvt_pkrtz(a, b);   // __fp16 ext_vector(2)
    return __builtin_bit_cast(unsigned, r);
}
__device__ __forceinline__ void swap32(unsigned& a, unsigned& b) {
    asm volatile("v_permlane32_swap_b32 %0, %1" : "+v"(a), "+v"(b));
}

// ---------------------------------------------------------------------------
// Weight f32 -> f16 pre-conversion (wk, wq, wv, wo -> W16[4][65536]).
// grid 128, block 256; each thread converts 8 elements.
// ---------------------------------------------------------------------------
__global__ __launch_bounds__(256) void wcvt(
    const float* __restrict__ w0, const float* __restrict__ w1,
    const float* __restrict__ w2, const float* __restrict__ w3,
    f16* __restrict__ O)
{
    const int id = blockIdx.x * 256 + threadIdx.x;   // 0..32767
    const int tsel = id >> 13;                        // 0..3
    const int off = (id & 8191) * 8;
    const float* src = tsel == 0 ? w0 : (tsel == 1 ? w1 : (tsel == 2 ? w2 : w3));
    const float4 a = *reinterpret_cast<const float4*>(src + off);
    const float4 b = *reinterpret_cast<const float4*>(src + off + 4);
    f16x8 o = {(f16)a.x, (f16)a.y, (f16)a.z, (f16)a.w,
               (f16)b.x, (f16)b.y, (f16)b.z, (f16)b.w};
    *reinterpret_cast<f16x8*>(&O[(size_t)tsel * 65536 + off]) = o;
}

// ---------------------------------------------------------------------------
// Fused K/Q/V projection v3: LDS-staged transposed x-tile (R18) + f16 W reads
// (halves W L2 traffic).  grid (36, 3, 4), block 256.
// Outputs: K,Q as [b][h][n][64c]; V as [b][h][64c][n].
// ---------------------------------------------------------------------------
__global__ __launch_bounds__(256) void proj_qkv_v3(
    const f16* __restrict__ W16,
    const float* __restrict__ bk, const float* __restrict__ bq,
    const float* __restrict__ bv,
    const float* __restrict__ X,
    f16* __restrict__ Kt, f16* __restrict__ Qt, f16* __restrict__ Vg)
{
    __shared__ __align__(16) char SMEM[40960];
    f16 (*T)[264]  = reinterpret_cast<f16(*)[264]>(SMEM);   // x-tile [64n][256c+pad]
    f16 (*Vt)[80]  = reinterpret_cast<f16(*)[80]>(SMEM);    // V out  [256c][64n+pad]

    const int t = threadIdx.x, l = t & 63, w = t >> 6;
    const int lm = l & 15, lg = l >> 4;
    const int n0 = blockIdx.x * 64;
    const int sel = blockIdx.y;
    const int b = blockIdx.z;

    const f16* W = W16 + (size_t)sel * 65536;
    const float* Bi = sel == 0 ? bk : (sel == 1 ? bq : bv);

    {
        const int cq = t >> 4;
        const int nq = (t & 15) * 4;
#pragma unroll
        for (int p = 0; p < 16; ++p) {
            const int c = p * 16 + cq;
            const float4 v = *reinterpret_cast<const float4*>(
                &X[((size_t)b * CH + c) * NT + n0 + nq]);
            T[nq + 0][c] = (f16)v.x;
            T[nq + 1][c] = (f16)v.y;
            T[nq + 2][c] = (f16)v.z;
            T[nq + 3][c] = (f16)v.w;
        }
    }
    __syncthreads();

    f32x4 acc[4][4] = {};   // [h][nt]

#pragma unroll 2
    for (int ks = 0; ks < 8; ++ks) {
        f16x8 bf[4];
#pragma unroll
        for (int nt = 0; nt < 4; ++nt)
            bf[nt] = *reinterpret_cast<const f16x8*>(
                &T[nt * 16 + lm][ks * 32 + lg * 8]);
#pragma unroll
        for (int h = 0; h < 4; ++h) {
            const f16x8 a = *reinterpret_cast<const f16x8*>(
                &W[(size_t)(h * 64 + w * 16 + lm) * CH + ks * 32 + lg * 8]);
#pragma unroll
            for (int nt = 0; nt < 4; ++nt)
                acc[h][nt] = MFMA16(a, bf[nt], acc[h][nt]);
        }
    }

    const int c_base = w * 16 + lg * 4;
    if (sel < 2) {
        f16* Out = sel == 0 ? Kt : Qt;
#pragma unroll
        for (int h = 0; h < 4; ++h) {
            const float4 b4 = *reinterpret_cast<const float4*>(&Bi[h * 64 + c_base]);
            const float bb[4] = {b4.x, b4.y, b4.z, b4.w};
#pragma unroll
            for (int nt = 0; nt < 4; ++nt) {
                const int n = n0 + nt * 16 + lm;
                f16x4 o = {(f16)(acc[h][nt][0] + bb[0]), (f16)(acc[h][nt][1] + bb[1]),
                           (f16)(acc[h][nt][2] + bb[2]), (f16)(acc[h][nt][3] + bb[3])};
                *reinterpret_cast<f16x4*>(
                    &Out[((size_t)((b * NHEADS + h) * NT + n)) * HC + c_base]) = o;
            }
        }
    } else {
        __syncthreads();   // x-tile dead; reuse SMEM as Vt[256][80]
#pragma unroll
        for (int h = 0; h < 4; ++h)
#pragma unroll
            for (int nt = 0; nt < 4; ++nt)
#pragma unroll
                for (int r = 0; r < 4; ++r)
                    Vt[h * 64 + c_base + r][nt * 16 + lm] = (f16)acc[h][nt][r];
        __syncthreads();
#pragma unroll
        for (int p = 0; p < 8; ++p) {
            const int c  = p * 32 + (t >> 3);
            const int nn = (t & 7) * 8;
            const float bb = Bi[c];
            const f16x8 vv = *reinterpret_cast<const f16x8*>(&Vt[c][nn]);
            f16x8 o;
#pragma unroll
            for (int j = 0; j < 8; ++j) o[j] = (f16)((float)vv[j] + bb);
            *reinterpret_cast<f16x8*>(
                &Vg[((size_t)((b * NHEADS + (c >> 6)) * HC + (c & 63))) * NT
                    + n0 + nn]) = o;
        }
    }
}

// ---------------------------------------------------------------------------
// Flash attention PASS 1: 128-query tiles, cross-block split-K x2.
// grid 576 = (18 qt x 2 seg x 16 bh, XCD-mapped), block 256 = 4 waves x 32q.
// Each 16KB K/V chunk serves 128 queries (staging 331 -> 166 MB total).
// Per-wave inner loop identical to R9 (proven). Output: normalized partial
// O (f16) + m, l (f32) per (seg, bh, qt, q) to workspace; exact merge in
// pass 2.  Stage roles: wave0/1 = K rows 0-31/32-63, wave2/3 = V likewise.
// ---------------------------------------------------------------------------
__global__ __launch_bounds__(256) void attn_p1(
    const f16* __restrict__ Kt, const f16* __restrict__ Qt,
    const f16* __restrict__ Vg,
    f16* __restrict__ Pa, float* __restrict__ Pm, float* __restrict__ Pl)
{
    __shared__ f16 SM[2][4096];   // [K/V][64 rows x 64c], 16 KB

    const int t = threadIdx.x, l = t & 63, w = t >> 6;
    const int col = l & 31, hi = l >> 5;

    const int bid = blockIdx.x;
    const int xcd = bid & 7, idx = bid >> 3;          // 72 per XCD
    const int second = idx >= 36 ? 1 : 0;
    const int bh = 2 * xcd + second;                  // 2 (b,h) pairs per XCD
    const int idx2 = idx - 36 * second;               // 0..35
    const int qt = idx2 >> 1, seg = idx2 & 1;
    const int b = bh >> 2, h = bh & 3;
    const int m0 = qt * 128;

    const size_t bhs = (size_t)(b * NHEADS + h);
    const f16* Kb = Kt + bhs * NT * HC;   // [n][64c]
    const f16* Qb = Qt + bhs * NT * HC;
    const f16* Vb = Vg + bhs * HC * NT;   // [c][n]

    const int srow = l >> 3, su = l & 7, sx = su ^ srow;

    const int q = m0 + w * 32 + col;
    f16x8 qf[4];
#pragma unroll
    for (int cs = 0; cs < 4; ++cs)
        qf[cs] = *reinterpret_cast<const f16x8*>(
            &Qb[(size_t)q * HC + cs * 16 + hi * 8]);

    const f32x16 Z16 = {0,0,0,0,0,0,0,0,0,0,0,0,0,0,0,0};
    f32x16 acc0 = Z16, acc1 = Z16;
    float m_run = -3.0e38f, l_run = 0.0f;

    const int kbase = seg * KSEG;

    // wave roles: w0/w1 stage K rows 0-31/32-63; w2/w3 stage V rows 0-31/32-63
    auto stage = [&](int kc) {
        const int half = (w & 1) * 32;
        if (w < 2) {
            const char* src = (const char*)(Kb + (size_t)kc * HC);
            char* dst = (char*)&SM[0][0];
#pragma unroll
            for (int g = 0; g < 4; ++g) {
                const int rb = half + g * 8;
                gload_lds16(src + (size_t)(rb + srow) * 128 + (sx << 4),
                            dst + rb * 128);
            }
        } else {
            const char* src = (const char*)Vb + (size_t)kc * 2;
            char* dst = (char*)&SM[1][0];
#pragma unroll
            for (int g = 0; g < 4; ++g) {
                const int rb = half + g * 8;
                gload_lds16(src + (size_t)(rb + srow) * (NT * 2) + (sx << 4),
                            dst + rb * 128);
            }
        }
    };

    auto rd = [&](const f16* base, int row, int u) -> f16x8 {
        return *reinterpret_cast<const f16x8*>(
            base + row * 64 + ((u ^ (row & 7)) << 3));
    };

    stage(kbase);
    __syncthreads();

    for (int i = 0; i < NSEG; ++i) {
        const f16* Kc = &SM[0][0];
        const f16* Vc = &SM[1][0];

        f32x16 s0 = Z16, s1 = Z16;
#pragma unroll
        for (int cs = 0; cs < 4; ++cs) {
            const f16x8 k0 = rd(Kc, col,      cs * 2 + hi);
            const f16x8 k1 = rd(Kc, 32 + col, cs * 2 + hi);
            s0 = MFMA32(k0, qf[cs], s0);
            s1 = MFMA32(k1, qf[cs], s1);
        }

        float m8[8];
#pragma unroll
        for (int j = 0; j < 8; ++j)
            m8[j] = fmaxf(fmaxf(s0[2 * j], s0[2 * j + 1]),
                          fmaxf(s1[2 * j], s1[2 * j + 1]));
        float cm = fmaxf(fmaxf(fmaxf(m8[0], m8[1]), fmaxf(m8[2], m8[3])),
                         fmaxf(fmaxf(m8[4], m8[5]), fmaxf(m8[6], m8[7])));
        cm = fmaxf(cm, __shfl_xor(cm, 32));
        if (!__all(cm <= m_run + 8.0f)) {     // defer-max, THR=8
            const float mN = fmaxf(m_run, cm);
            const float fac = __expf(m_run - mN);
#pragma unroll
            for (int r = 0; r < 16; ++r) { acc0[r] *= fac; acc1[r] *= fac; }
            l_run *= fac;
            m_run = mN;
        }
        float p0[16], p1[16];
        float ps0 = 0.f, ps1 = 0.f, ps2 = 0.f, ps3 = 0.f;
#pragma unroll
        for (int r = 0; r < 4; ++r) {
            p0[r]      = __expf(s0[r]      - m_run); ps0 += p0[r];
            p0[r + 4]  = __expf(s0[r + 4]  - m_run); ps1 += p0[r + 4];
            p0[r + 8]  = __expf(s0[r + 8]  - m_run); ps2 += p0[r + 8];
            p0[r + 12] = __expf(s0[r + 12] - m_run); ps3 += p0[r + 12];
            p1[r]      = __expf(s1[r]      - m_run); ps0 += p1[r];
            p1[r + 4]  = __expf(s1[r + 4]  - m_run); ps1 += p1[r + 4];
            p1[r + 8]  = __expf(s1[r + 8]  - m_run); ps2 += p1[r + 8];
            p1[r + 12] = __expf(s1[r + 12] - m_run); ps3 += p1[r + 12];
        }
        l_run += (ps0 + ps1) + (ps2 + ps3);

        unsigned a0[8], a1[8];
#pragma unroll
        for (int j = 0; j < 8; ++j) {
            a0[j] = pkh(p0[2 * j], p0[2 * j + 1]);
            a1[j] = pkh(p1[2 * j], p1[2 * j + 1]);
        }
        swap32(a0[0], a0[2]); swap32(a0[1], a0[3]);
        swap32(a0[4], a0[6]); swap32(a0[5], a0[7]);
        swap32(a1[0], a1[2]); swap32(a1[1], a1[3]);
        swap32(a1[4], a1[6]); swap32(a1[5], a1[7]);
        union BU { unsigned u[4]; f16x8 v; };
        BU fr[4];
        fr[0].u[0] = a0[0]; fr[0].u[1] = a0[1]; fr[0].u[2] = a0[2]; fr[0].u[3] = a0[3];
        fr[1].u[0] = a0[4]; fr[1].u[1] = a0[5]; fr[1].u[2] = a0[6]; fr[1].u[3] = a0[7];
        fr[2].u[0] = a1[0]; fr[2].u[1] = a1[1]; fr[2].u[2] = a1[2]; fr[2].u[3] = a1[3];
        fr[3].u[0] = a1[4]; fr[3].u[1] = a1[5]; fr[3].u[2] = a1[6]; fr[3].u[3] = a1[7];

#pragma unroll
        for (int kk = 0; kk < 4; ++kk) {
            const f16x8 v0 = rd(Vc, col,      kk * 2 + hi);
            const f16x8 v1 = rd(Vc, 32 + col, kk * 2 + hi);
            acc0 = MFMA32(v0, fr[kk].v, acc0);
            acc1 = MFMA32(v1, fr[kk].v, acc1);
        }

        __syncthreads();
        if (i + 1 < NSEG) {
            stage(kbase + (i + 1) * 64);
            __syncthreads();
        }
    }

    // ---- publish normalized partials (no block-level merge needed) ------
    const float l_full = l_run + __shfl_xor(l_run, 32);
    const float inv = 1.0f / l_full;
    const size_t pq = ((size_t)((seg * 16 + bh) * NQT + qt)) * 128 + w * 32 + col;
    if (hi == 0) { Pm[pq] = m_run; Pl[pq] = l_full; }
    f16* row = Pa + pq * 64;
#pragma unroll
    for (int rq = 0; rq < 4; ++rq) {
        const int c0 = rq * 8 + hi * 4;
        f16x4 o0 = {(f16)(acc0[rq * 4 + 0] * inv), (f16)(acc0[rq * 4 + 1] * inv),
                    (f16)(acc0[rq * 4 + 2] * inv), (f16)(acc0[rq * 4 + 3] * inv)};
        f16x4 o1 = {(f16)(acc1[rq * 4 + 0] * inv), (f16)(acc1[rq * 4 + 1] * inv),
                    (f16)(acc1[rq * 4 + 2] * inv), (f16)(acc1[rq * 4 + 3] * inv)};
        *reinterpret_cast<f16x4*>(row + c0) = o0;
        *reinterpret_cast<f16x4*>(row + 32 + c0) = o1;
    }
}

// ---------------------------------------------------------------------------
// Flash attention PASS 2: exact 2-segment merge.
// grid (18, 16) = (qt, bh), block 256; thread t: q = t>>1, channels (t&1)*32.
// out = (cA*aA + cB*aB)/(cA+cB), ci = exp(mi - M)*li.
// ---------------------------------------------------------------------------
__global__ __launch_bounds__(256) void attn_mg(
    const f16* __restrict__ Pa, const float* __restrict__ Pm,
    const float* __restrict__ Pl, f16* __restrict__ Ot)
{
    const int t = threadIdx.x;
    const int qt = blockIdx.x, bh = blockIdx.y;
    const int b = bh >> 2, h = bh & 3;
    const int ql = t >> 1, c0 = (t & 1) * 32;

    const size_t i0 = ((size_t)((0 * 16 + bh) * NQT + qt)) * 128 + ql;
    const size_t i1 = ((size_t)((1 * 16 + bh) * NQT + qt)) * 128 + ql;
    const float mA = Pm[i0], mB = Pm[i1];
    const float M = fmaxf(mA, mB);
    const float cA = __expf(mA - M) * Pl[i0];
    const float cB = __expf(mB - M) * Pl[i1];
    const float inv = 1.0f / (cA + cB);

    const f16* rA = Pa + i0 * 64 + c0;
    const f16* rB = Pa + i1 * 64 + c0;
    f16* dst = &Ot[((size_t)(b * NT + qt * 128 + ql)) * CH + h * HC + c0];
#pragma unroll
    for (int j4 = 0; j4 < 4; ++j4) {
        const f16x8 aA = *reinterpret_cast<const f16x8*>(rA + j4 * 8);
        const f16x8 aB = *reinterpret_cast<const f16x8*>(rB + j4 * 8);
        f16x8 o;
#pragma unroll
        for (int j = 0; j < 8; ++j)
            o[j] = (f16)((cA * (float)aA[j] + cB * (float)aB[j]) * inv);
        *reinterpret_cast<f16x8*>(dst + j4 * 8) = o;
    }
}

// ---------------------------------------------------------------------------
// Final conv1x1 with f16 wo (halves wo L2 traffic). grid (36, 4, 4).
// ---------------------------------------------------------------------------
__global__ __launch_bounds__(256) void out_gemm_v2(
    const f16* __restrict__ wo16, const float* __restrict__ bo,
    const f16* __restrict__ Ot, float* __restrict__ Y)
{
    const int t = threadIdx.x, l = t & 63, w = t >> 6;
    const int lm = l & 15, lg = l >> 4;
    const int n0 = blockIdx.x * 64;
    const int o0 = blockIdx.y * 64;
    const int b = blockIdx.z;

    f32x4 acc[4] = {{0.f,0.f,0.f,0.f},{0.f,0.f,0.f,0.f},
                    {0.f,0.f,0.f,0.f},{0.f,0.f,0.f,0.f}};
    const int o_row = o0 + w * 16 + lm;

#pragma unroll
    for (int ks = 0; ks < 8; ++ks) {
        const f16x8 a = *reinterpret_cast<const f16x8*>(
            &wo16[(size_t)o_row * CH + ks * 32 + lg * 8]);
#pragma unroll
        for (int nt = 0; nt < 4; ++nt) {
            const f16x8 bf = *reinterpret_cast<const f16x8*>(
                &Ot[((size_t)(b * NT + n0 + nt * 16 + lm)) * CH + ks * 32 + lg * 8]);
            acc[nt] = MFMA16(a, bf, acc[nt]);
        }
    }

    const int ob = o0 + w * 16 + lg * 4;
    const float4 bias4 = *reinterpret_cast<const float4*>(&bo[ob]);
    const float bb[4] = {bias4.x, bias4.y, bias4.z, bias4.w};
#pragma unroll
    for (int nt = 0; nt < 4; ++nt) {
        const int n = n0 + nt * 16 + lm;
#pragma unroll
        for (int r = 0; r < 4; ++r)
            Y[((size_t)(b * CH + ob + r)) * NT + n] = acc[nt][r] + bb[r];
    }
}

// ---------------------------------------------------------------------------
extern "C" void kernel_launch(void* const* d_in, const int* in_sizes, int n_in,
                              void* d_out, int out_size, void* d_ws, size_t ws_size,
                              hipStream_t stream) {
    (void)in_sizes; (void)n_in; (void)out_size; (void)ws_size;
    const float* x  = (const float*)d_in[0];
    const float* wk = (const float*)d_in[1];
    const float* bk = (const float*)d_in[2];
    const float* wq = (const float*)d_in[3];
    const float* bq = (const float*)d_in[4];
    const float* wv = (const float*)d_in[5];
    const float* bv = (const float*)d_in[6];
    const float* wo = (const float*)d_in[7];
    const float* bo = (const float*)d_in[8];
    float* out = (float*)d_out;

    const size_t SZ = (size_t)NB * NT * CH;           // 2,359,296 f16 per tensor
    f16* Kt  = (f16*)d_ws;                            // [b][h][n][c]
    f16* Qt  = Kt + SZ;                               // [b][h][n][c]
    f16* Vg  = Qt + SZ;                               // [b][h][c][n]
    f16* Ot  = Vg + SZ;                               // [b][n][c]
    f16* W16 = Ot + SZ;                               // [4][65536] f16
    f16* Pa  = W16 + 4 * 65536;                       // [2][16][18][128][64] f16
    float* Pm = (float*)(Pa + (size_t)2 * 16 * NQT * 128 * 64);
    float* Pl = Pm + (size_t)2 * 16 * NQT * 128;      // total ws ~29.4 MB

    wcvt<<<dim3(128), 256, 0, stream>>>(wk, wq, wv, wo, W16);
    proj_qkv_v3<<<dim3(36, 3, 4), 256, 0, stream>>>(
        W16, bk, bq, bv, x, Kt, Qt, Vg);
    attn_p1<<<dim3(576), 256, 0, stream>>>(Kt, Qt, Vg, Pa, Pm, Pl);
    attn_mg<<<dim3(18, 16), 256, 0, stream>>>(Pa, Pm, Pl, Ot);
    out_gemm_v2<<<dim3(36, 4, 4), 256, 0, stream>>>(
        W16 + 3 * 65536, bo, Ot, out);
}

// Round 21
// 97.702 us; speedup vs baseline: 2.2873x; 1.0312x over previous
//
#include <hip/hip_runtime.h>
#include <math.h>

#define NB 4
#define CH 256
#define NHEADS 4
#define HC 64
#define NT 2304    // 48*48
#define NSEGS 4    // split-K segments (cross-block)
#define KSEG 576   // keys per segment
#define NSEG 9     // 64-key chunks per segment
#define NQT 18     // 128-query tiles

typedef _Float16 f16;
typedef _Float16 f16x4 __attribute__((ext_vector_type(4)));
typedef _Float16 f16x8 __attribute__((ext_vector_type(8)));
typedef float f32x4 __attribute__((ext_vector_type(4)));
typedef float f32x16 __attribute__((ext_vector_type(16)));

#define MFMA16(a, b, c) __builtin_amdgcn_mfma_f32_16x16x32_f16(a, b, c, 0, 0, 0)
#define MFMA32(a, b, c) __builtin_amdgcn_mfma_f32_32x32x16_f16(a, b, c, 0, 0, 0)

__device__ __forceinline__ void gload_lds16(const void* g, void* l) {
    __builtin_amdgcn_global_load_lds(
        (const __attribute__((address_space(1))) unsigned int*)g,
        (__attribute__((address_space(3))) unsigned int*)l, 16, 0, 0);
}

__device__ __forceinline__ unsigned pkh(float a, float b) {
    auto r = __builtin_amdgcn_cvt_pkrtz(a, b);   // __fp16 ext_vector(2)
    return __builtin_bit_cast(unsigned, r);
}
__device__ __forceinline__ void swap32(unsigned& a, unsigned& b) {
    asm volatile("v_permlane32_swap_b32 %0, %1" : "+v"(a), "+v"(b));
}

// ---------------------------------------------------------------------------
// Weight f32 -> f16 pre-conversion (wk, wq, wv, wo -> W16[4][65536]).
// ---------------------------------------------------------------------------
__global__ __launch_bounds__(256) void wcvt(
    const float* __restrict__ w0, const float* __restrict__ w1,
    const float* __restrict__ w2, const float* __restrict__ w3,
    f16* __restrict__ O)
{
    const int id = blockIdx.x * 256 + threadIdx.x;   // 0..32767
    const int tsel = id >> 13;                        // 0..3
    const int off = (id & 8191) * 8;
    const float* src = tsel == 0 ? w0 : (tsel == 1 ? w1 : (tsel == 2 ? w2 : w3));
    const float4 a = *reinterpret_cast<const float4*>(src + off);
    const float4 b = *reinterpret_cast<const float4*>(src + off + 4);
    f16x8 o = {(f16)a.x, (f16)a.y, (f16)a.z, (f16)a.w,
               (f16)b.x, (f16)b.y, (f16)b.z, (f16)b.w};
    *reinterpret_cast<f16x8*>(&O[(size_t)tsel * 65536 + off]) = o;
}

// ---------------------------------------------------------------------------
// Fused K/Q/V projection v3 (unchanged from R20). grid (36, 3, 4), block 256.
// ---------------------------------------------------------------------------
__global__ __launch_bounds__(256) void proj_qkv_v3(
    const f16* __restrict__ W16,
    const float* __restrict__ bk, const float* __restrict__ bq,
    const float* __restrict__ bv,
    const float* __restrict__ X,
    f16* __restrict__ Kt, f16* __restrict__ Qt, f16* __restrict__ Vg)
{
    __shared__ __align__(16) char SMEM[40960];
    f16 (*T)[264]  = reinterpret_cast<f16(*)[264]>(SMEM);   // x-tile [64n][256c+pad]
    f16 (*Vt)[80]  = reinterpret_cast<f16(*)[80]>(SMEM);    // V out  [256c][64n+pad]

    const int t = threadIdx.x, l = t & 63, w = t >> 6;
    const int lm = l & 15, lg = l >> 4;
    const int n0 = blockIdx.x * 64;
    const int sel = blockIdx.y;
    const int b = blockIdx.z;

    const f16* W = W16 + (size_t)sel * 65536;
    const float* Bi = sel == 0 ? bk : (sel == 1 ? bq : bv);

    {
        const int cq = t >> 4;
        const int nq = (t & 15) * 4;
#pragma unroll
        for (int p = 0; p < 16; ++p) {
            const int c = p * 16 + cq;
            const float4 v = *reinterpret_cast<const float4*>(
                &X[((size_t)b * CH + c) * NT + n0 + nq]);
            T[nq + 0][c] = (f16)v.x;
            T[nq + 1][c] = (f16)v.y;
            T[nq + 2][c] = (f16)v.z;
            T[nq + 3][c] = (f16)v.w;
        }
    }
    __syncthreads();

    f32x4 acc[4][4] = {};   // [h][nt]

#pragma unroll 2
    for (int ks = 0; ks < 8; ++ks) {
        f16x8 bf[4];
#pragma unroll
        for (int nt = 0; nt < 4; ++nt)
            bf[nt] = *reinterpret_cast<const f16x8*>(
                &T[nt * 16 + lm][ks * 32 + lg * 8]);
#pragma unroll
        for (int h = 0; h < 4; ++h) {
            const f16x8 a = *reinterpret_cast<const f16x8*>(
                &W[(size_t)(h * 64 + w * 16 + lm) * CH + ks * 32 + lg * 8]);
#pragma unroll
            for (int nt = 0; nt < 4; ++nt)
                acc[h][nt] = MFMA16(a, bf[nt], acc[h][nt]);
        }
    }

    const int c_base = w * 16 + lg * 4;
    if (sel < 2) {
        f16* Out = sel == 0 ? Kt : Qt;
#pragma unroll
        for (int h = 0; h < 4; ++h) {
            const float4 b4 = *reinterpret_cast<const float4*>(&Bi[h * 64 + c_base]);
            const float bb[4] = {b4.x, b4.y, b4.z, b4.w};
#pragma unroll
            for (int nt = 0; nt < 4; ++nt) {
                const int n = n0 + nt * 16 + lm;
                f16x4 o = {(f16)(acc[h][nt][0] + bb[0]), (f16)(acc[h][nt][1] + bb[1]),
                           (f16)(acc[h][nt][2] + bb[2]), (f16)(acc[h][nt][3] + bb[3])};
                *reinterpret_cast<f16x4*>(
                    &Out[((size_t)((b * NHEADS + h) * NT + n)) * HC + c_base]) = o;
            }
        }
    } else {
        __syncthreads();   // x-tile dead; reuse SMEM as Vt[256][80]
#pragma unroll
        for (int h = 0; h < 4; ++h)
#pragma unroll
            for (int nt = 0; nt < 4; ++nt)
#pragma unroll
                for (int r = 0; r < 4; ++r)
                    Vt[h * 64 + c_base + r][nt * 16 + lm] = (f16)acc[h][nt][r];
        __syncthreads();
#pragma unroll
        for (int p = 0; p < 8; ++p) {
            const int c  = p * 32 + (t >> 3);
            const int nn = (t & 7) * 8;
            const float bb = Bi[c];
            const f16x8 vv = *reinterpret_cast<const f16x8*>(&Vt[c][nn]);
            f16x8 o;
#pragma unroll
            for (int j = 0; j < 8; ++j) o[j] = (f16)((float)vv[j] + bb);
            *reinterpret_cast<f16x8*>(
                &Vg[((size_t)((b * NHEADS + (c >> 6)) * HC + (c & 63))) * NT
                    + n0 + nn]) = o;
        }
    }
}

// ---------------------------------------------------------------------------
// Flash attention PASS 1: 128-query tiles, cross-block SPLIT-K x4.
// grid 1152 = (18 qt x 4 seg x 16 bh, XCD-mapped) -> 4.5 blocks/CU (2x R20's
// occupancy) at UNCHANGED total staged traffic (166 MB; each 16KB chunk still
// serves 128 queries). Critical path 9 chunks. Per-wave code = R20/R9.
// block 256 = 4 waves x 32q. Stage roles: w0/w1 = K halves, w2/w3 = V halves.
// ---------------------------------------------------------------------------
__global__ __launch_bounds__(256) void attn_p1(
    const f16* __restrict__ Kt, const f16* __restrict__ Qt,
    const f16* __restrict__ Vg,
    f16* __restrict__ Pa, float* __restrict__ Pm, float* __restrict__ Pl)
{
    __shared__ f16 SM[2][4096];   // [K/V][64 rows x 64c], 16 KB

    const int t = threadIdx.x, l = t & 63, w = t >> 6;
    const int col = l & 31, hi = l >> 5;

    const int bid = blockIdx.x;
    const int xcd = bid & 7, idx = bid >> 3;          // 144 per XCD
    const int second = idx >= 72 ? 1 : 0;
    const int bh = 2 * xcd + second;                  // 2 (b,h) pairs per XCD
    const int idx2 = idx - 72 * second;               // 0..71
    const int qt = idx2 >> 2, seg = idx2 & 3;
    const int b = bh >> 2, h = bh & 3;
    const int m0 = qt * 128;

    const size_t bhs = (size_t)(b * NHEADS + h);
    const f16* Kb = Kt + bhs * NT * HC;   // [n][64c]
    const f16* Qb = Qt + bhs * NT * HC;
    const f16* Vb = Vg + bhs * HC * NT;   // [c][n]

    const int srow = l >> 3, su = l & 7, sx = su ^ srow;

    const int q = m0 + w * 32 + col;
    f16x8 qf[4];
#pragma unroll
    for (int cs = 0; cs < 4; ++cs)
        qf[cs] = *reinterpret_cast<const f16x8*>(
            &Qb[(size_t)q * HC + cs * 16 + hi * 8]);

    const f32x16 Z16 = {0,0,0,0,0,0,0,0,0,0,0,0,0,0,0,0};
    f32x16 acc0 = Z16, acc1 = Z16;
    float m_run = -3.0e38f, l_run = 0.0f;

    const int kbase = seg * KSEG;

    auto stage = [&](int kc) {
        const int half = (w & 1) * 32;
        if (w < 2) {
            const char* src = (const char*)(Kb + (size_t)kc * HC);
            char* dst = (char*)&SM[0][0];
#pragma unroll
            for (int g = 0; g < 4; ++g) {
                const int rb = half + g * 8;
                gload_lds16(src + (size_t)(rb + srow) * 128 + (sx << 4),
                            dst + rb * 128);
            }
        } else {
            const char* src = (const char*)Vb + (size_t)kc * 2;
            char* dst = (char*)&SM[1][0];
#pragma unroll
            for (int g = 0; g < 4; ++g) {
                const int rb = half + g * 8;
                gload_lds16(src + (size_t)(rb + srow) * (NT * 2) + (sx << 4),
                            dst + rb * 128);
            }
        }
    };

    auto rd = [&](const f16* base, int row, int u) -> f16x8 {
        return *reinterpret_cast<const f16x8*>(
            base + row * 64 + ((u ^ (row & 7)) << 3));
    };

    stage(kbase);
    __syncthreads();

    for (int i = 0; i < NSEG; ++i) {
        const f16* Kc = &SM[0][0];
        const f16* Vc = &SM[1][0];

        f32x16 s0 = Z16, s1 = Z16;
#pragma unroll
        for (int cs = 0; cs < 4; ++cs) {
            const f16x8 k0 = rd(Kc, col,      cs * 2 + hi);
            const f16x8 k1 = rd(Kc, 32 + col, cs * 2 + hi);
            s0 = MFMA32(k0, qf[cs], s0);
            s1 = MFMA32(k1, qf[cs], s1);
        }

        float m8[8];
#pragma unroll
        for (int j = 0; j < 8; ++j)
            m8[j] = fmaxf(fmaxf(s0[2 * j], s0[2 * j + 1]),
                          fmaxf(s1[2 * j], s1[2 * j + 1]));
        float cm = fmaxf(fmaxf(fmaxf(m8[0], m8[1]), fmaxf(m8[2], m8[3])),
                         fmaxf(fmaxf(m8[4], m8[5]), fmaxf(m8[6], m8[7])));
        cm = fmaxf(cm, __shfl_xor(cm, 32));
        if (!__all(cm <= m_run + 8.0f)) {     // defer-max, THR=8
            const float mN = fmaxf(m_run, cm);
            const float fac = __expf(m_run - mN);
#pragma unroll
            for (int r = 0; r < 16; ++r) { acc0[r] *= fac; acc1[r] *= fac; }
            l_run *= fac;
            m_run = mN;
        }
        float p0[16], p1[16];
        float ps0 = 0.f, ps1 = 0.f, ps2 = 0.f, ps3 = 0.f;
#pragma unroll
        for (int r = 0; r < 4; ++r) {
            p0[r]      = __expf(s0[r]      - m_run); ps0 += p0[r];
            p0[r + 4]  = __expf(s0[r + 4]  - m_run); ps1 += p0[r + 4];
            p0[r + 8]  = __expf(s0[r + 8]  - m_run); ps2 += p0[r + 8];
            p0[r + 12] = __expf(s0[r + 12] - m_run); ps3 += p0[r + 12];
            p1[r]      = __expf(s1[r]      - m_run); ps0 += p1[r];
            p1[r + 4]  = __expf(s1[r + 4]  - m_run); ps1 += p1[r + 4];
            p1[r + 8]  = __expf(s1[r + 8]  - m_run); ps2 += p1[r + 8];
            p1[r + 12] = __expf(s1[r + 12] - m_run); ps3 += p1[r + 12];
        }
        l_run += (ps0 + ps1) + (ps2 + ps3);

        unsigned a0[8], a1[8];
#pragma unroll
        for (int j = 0; j < 8; ++j) {
            a0[j] = pkh(p0[2 * j], p0[2 * j + 1]);
            a1[j] = pkh(p1[2 * j], p1[2 * j + 1]);
        }
        swap32(a0[0], a0[2]); swap32(a0[1], a0[3]);
        swap32(a0[4], a0[6]); swap32(a0[5], a0[7]);
        swap32(a1[0], a1[2]); swap32(a1[1], a1[3]);
        swap32(a1[4], a1[6]); swap32(a1[5], a1[7]);
        union BU { unsigned u[4]; f16x8 v; };
        BU fr[4];
        fr[0].u[0] = a0[0]; fr[0].u[1] = a0[1]; fr[0].u[2] = a0[2]; fr[0].u[3] = a0[3];
        fr[1].u[0] = a0[4]; fr[1].u[1] = a0[5]; fr[1].u[2] = a0[6]; fr[1].u[3] = a0[7];
        fr[2].u[0] = a1[0]; fr[2].u[1] = a1[1]; fr[2].u[2] = a1[2]; fr[2].u[3] = a1[3];
        fr[3].u[0] = a1[4]; fr[3].u[1] = a1[5]; fr[3].u[2] = a1[6]; fr[3].u[3] = a1[7];

#pragma unroll
        for (int kk = 0; kk < 4; ++kk) {
            const f16x8 v0 = rd(Vc, col,      kk * 2 + hi);
            const f16x8 v1 = rd(Vc, 32 + col, kk * 2 + hi);
            acc0 = MFMA32(v0, fr[kk].v, acc0);
            acc1 = MFMA32(v1, fr[kk].v, acc1);
        }

        __syncthreads();
        if (i + 1 < NSEG) {
            stage(kbase + (i + 1) * 64);
            __syncthreads();
        }
    }

    // ---- publish normalized partials ------------------------------------
    const float l_full = l_run + __shfl_xor(l_run, 32);
    const float inv = 1.0f / l_full;
    const size_t pq = ((size_t)((seg * 16 + bh) * NQT + qt)) * 128 + w * 32 + col;
    if (hi == 0) { Pm[pq] = m_run; Pl[pq] = l_full; }
    f16* row = Pa + pq * 64;
#pragma unroll
    for (int rq = 0; rq < 4; ++rq) {
        const int c0 = rq * 8 + hi * 4;
        f16x4 o0 = {(f16)(acc0[rq * 4 + 0] * inv), (f16)(acc0[rq * 4 + 1] * inv),
                    (f16)(acc0[rq * 4 + 2] * inv), (f16)(acc0[rq * 4 + 3] * inv)};
        f16x4 o1 = {(f16)(acc1[rq * 4 + 0] * inv), (f16)(acc1[rq * 4 + 1] * inv),
                    (f16)(acc1[rq * 4 + 2] * inv), (f16)(acc1[rq * 4 + 3] * inv)};
        *reinterpret_cast<f16x4*>(row + c0) = o0;
        *reinterpret_cast<f16x4*>(row + 32 + c0) = o1;
    }
}

// ---------------------------------------------------------------------------
// Flash attention PASS 2: exact 4-segment merge.
// grid (18, 16) = (qt, bh), block 256; thread t: q = t>>1, channels (t&1)*32.
// ---------------------------------------------------------------------------
__global__ __launch_bounds__(256) void attn_mg(
    const f16* __restrict__ Pa, const float* __restrict__ Pm,
    const float* __restrict__ Pl, f16* __restrict__ Ot)
{
    const int t = threadIdx.x;
    const int qt = blockIdx.x, bh = blockIdx.y;
    const int b = bh >> 2, h = bh & 3;
    const int ql = t >> 1, c0 = (t & 1) * 32;

    size_t ix[NSEGS];
    float m[NSEGS], c[NSEGS];
    float M = -3.0e38f;
#pragma unroll
    for (int s = 0; s < NSEGS; ++s) {
        ix[s] = ((size_t)((s * 16 + bh) * NQT + qt)) * 128 + ql;
        m[s] = Pm[ix[s]];
        M = fmaxf(M, m[s]);
    }
    float csum = 0.f;
#pragma unroll
    for (int s = 0; s < NSEGS; ++s) {
        c[s] = __expf(m[s] - M) * Pl[ix[s]];
        csum += c[s];
    }
    const float inv = 1.0f / csum;

    f16* dst = &Ot[((size_t)(b * NT + qt * 128 + ql)) * CH + h * HC + c0];
#pragma unroll
    for (int j4 = 0; j4 < 4; ++j4) {
        float v[8] = {};
#pragma unroll
        for (int s = 0; s < NSEGS; ++s) {
            const f16x8 a = *reinterpret_cast<const f16x8*>(
                Pa + ix[s] * 64 + c0 + j4 * 8);
#pragma unroll
            for (int j = 0; j < 8; ++j) v[j] += c[s] * (float)a[j];
        }
        f16x8 o;
#pragma unroll
        for (int j = 0; j < 8; ++j) o[j] = (f16)(v[j] * inv);
        *reinterpret_cast<f16x8*>(dst + j4 * 8) = o;
    }
}

// ---------------------------------------------------------------------------
// Final conv1x1 with f16 wo (unchanged from R20). grid (36, 4, 4).
// ---------------------------------------------------------------------------
__global__ __launch_bounds__(256) void out_gemm_v2(
    const f16* __restrict__ wo16, const float* __restrict__ bo,
    const f16* __restrict__ Ot, float* __restrict__ Y)
{
    const int t = threadIdx.x, l = t & 63, w = t >> 6;
    const int lm = l & 15, lg = l >> 4;
    const int n0 = blockIdx.x * 64;
    const int o0 = blockIdx.y * 64;
    const int b = blockIdx.z;

    f32x4 acc[4] = {{0.f,0.f,0.f,0.f},{0.f,0.f,0.f,0.f},
                    {0.f,0.f,0.f,0.f},{0.f,0.f,0.f,0.f}};
    const int o_row = o0 + w * 16 + lm;

#pragma unroll
    for (int ks = 0; ks < 8; ++ks) {
        const f16x8 a = *reinterpret_cast<const f16x8*>(
            &wo16[(size_t)o_row * CH + ks * 32 + lg * 8]);
#pragma unroll
        for (int nt = 0; nt < 4; ++nt) {
            const f16x8 bf = *reinterpret_cast<const f16x8*>(
                &Ot[((size_t)(b * NT + n0 + nt * 16 + lm)) * CH + ks * 32 + lg * 8]);
            acc[nt] = MFMA16(a, bf, acc[nt]);
        }
    }

    const int ob = o0 + w * 16 + lg * 4;
    const float4 bias4 = *reinterpret_cast<const float4*>(&bo[ob]);
    const float bb[4] = {bias4.x, bias4.y, bias4.z, bias4.w};
#pragma unroll
    for (int nt = 0; nt < 4; ++nt) {
        const int n = n0 + nt * 16 + lm;
#pragma unroll
        for (int r = 0; r < 4; ++r)
            Y[((size_t)(b * CH + ob + r)) * NT + n] = acc[nt][r] + bb[r];
    }
}

// ---------------------------------------------------------------------------
extern "C" void kernel_launch(void* const* d_in, const int* in_sizes, int n_in,
                              void* d_out, int out_size, void* d_ws, size_t ws_size,
                              hipStream_t stream) {
    (void)in_sizes; (void)n_in; (void)out_size; (void)ws_size;
    const float* x  = (const float*)d_in[0];
    const float* wk = (const float*)d_in[1];
    const float* bk = (const float*)d_in[2];
    const float* wq = (const float*)d_in[3];
    const float* bq = (const float*)d_in[4];
    const float* wv = (const float*)d_in[5];
    const float* bv = (const float*)d_in[6];
    const float* wo = (const float*)d_in[7];
    const float* bo = (const float*)d_in[8];
    float* out = (float*)d_out;

    const size_t SZ = (size_t)NB * NT * CH;           // 2,359,296 f16 per tensor
    f16* Kt  = (f16*)d_ws;                            // [b][h][n][c]
    f16* Qt  = Kt + SZ;                               // [b][h][n][c]
    f16* Vg  = Qt + SZ;                               // [b][h][c][n]
    f16* Ot  = Vg + SZ;                               // [b][n][c]
    f16* W16 = Ot + SZ;                               // [4][65536] f16
    f16* Pa  = W16 + 4 * 65536;                       // [4][16][18][128][64] f16
    float* Pm = (float*)(Pa + (size_t)NSEGS * 16 * NQT * 128 * 64);
    float* Pl = Pm + (size_t)NSEGS * 16 * NQT * 128;  // total ws ~40 MB

    wcvt<<<dim3(128), 256, 0, stream>>>(wk, wq, wv, wo, W16);
    proj_qkv_v3<<<dim3(36, 3, 4), 256, 0, stream>>>(
        W16, bk, bq, bv, x, Kt, Qt, Vg);
    attn_p1<<<dim3(1152), 256, 0, stream>>>(Kt, Qt, Vg, Pa, Pm, Pl);
    attn_mg<<<dim3(18, 16), 256, 0, stream>>>(Pa, Pm, Pl, Ot);
    out_gemm_v2<<<dim3(36, 4, 4), 256, 0, stream>>>(
        W16 + 3 * 65536, bo, Ot, out);
}

// Round 22
// 86.357 us; speedup vs baseline: 2.5877x; 1.1314x over previous
//
#include <hip/hip_runtime.h>
#include <math.h>

#define NB 4
#define CH 256
#define NHEADS 4
#define HC 64
#define NT 2304    // 48*48
#define NSEGS 4    // split-K segments (cross-block)
#define KSEG 576   // keys per segment
#define NSEG 9     // 64-key chunks per segment
#define NQT 18     // 128-query tiles

typedef _Float16 f16;
typedef _Float16 f16x4 __attribute__((ext_vector_type(4)));
typedef _Float16 f16x8 __attribute__((ext_vector_type(8)));
typedef float f32x4 __attribute__((ext_vector_type(4)));
typedef float f32x16 __attribute__((ext_vector_type(16)));

#define MFMA16(a, b, c) __builtin_amdgcn_mfma_f32_16x16x32_f16(a, b, c, 0, 0, 0)
#define MFMA32(a, b, c) __builtin_amdgcn_mfma_f32_32x32x16_f16(a, b, c, 0, 0, 0)

__device__ __forceinline__ void gload_lds16(const void* g, void* l) {
    __builtin_amdgcn_global_load_lds(
        (const __attribute__((address_space(1))) unsigned int*)g,
        (__attribute__((address_space(3))) unsigned int*)l, 16, 0, 0);
}

__device__ __forceinline__ unsigned pkh(float a, float b) {
    auto r = __builtin_amdgcn_cvt_pkrtz(a, b);   // __fp16 ext_vector(2)
    return __builtin_bit_cast(unsigned, r);
}
__device__ __forceinline__ void swap32(unsigned& a, unsigned& b) {
    asm volatile("v_permlane32_swap_b32 %0, %1" : "+v"(a), "+v"(b));
}

// ---------------------------------------------------------------------------
// Weight f32 -> f16 pre-conversion (wk, wq, wv, wo -> W16[4][65536]).
// ---------------------------------------------------------------------------
__global__ __launch_bounds__(256) void wcvt(
    const float* __restrict__ w0, const float* __restrict__ w1,
    const float* __restrict__ w2, const float* __restrict__ w3,
    f16* __restrict__ O)
{
    const int id = blockIdx.x * 256 + threadIdx.x;   // 0..32767
    const int tsel = id >> 13;                        // 0..3
    const int off = (id & 8191) * 8;
    const float* src = tsel == 0 ? w0 : (tsel == 1 ? w1 : (tsel == 2 ? w2 : w3));
    const float4 a = *reinterpret_cast<const float4*>(src + off);
    const float4 b = *reinterpret_cast<const float4*>(src + off + 4);
    f16x8 o = {(f16)a.x, (f16)a.y, (f16)a.z, (f16)a.w,
               (f16)b.x, (f16)b.y, (f16)b.z, (f16)b.w};
    *reinterpret_cast<f16x8*>(&O[(size_t)tsel * 65536 + off]) = o;
}

// ---------------------------------------------------------------------------
// Fused K/Q/V projection v3 (unchanged from R20/R21). grid (36, 3, 4).
// ---------------------------------------------------------------------------
__global__ __launch_bounds__(256) void proj_qkv_v3(
    const f16* __restrict__ W16,
    const float* __restrict__ bk, const float* __restrict__ bq,
    const float* __restrict__ bv,
    const float* __restrict__ X,
    f16* __restrict__ Kt, f16* __restrict__ Qt, f16* __restrict__ Vg)
{
    __shared__ __align__(16) char SMEM[40960];
    f16 (*T)[264]  = reinterpret_cast<f16(*)[264]>(SMEM);   // x-tile [64n][256c+pad]
    f16 (*Vt)[80]  = reinterpret_cast<f16(*)[80]>(SMEM);    // V out  [256c][64n+pad]

    const int t = threadIdx.x, l = t & 63, w = t >> 6;
    const int lm = l & 15, lg = l >> 4;
    const int n0 = blockIdx.x * 64;
    const int sel = blockIdx.y;
    const int b = blockIdx.z;

    const f16* W = W16 + (size_t)sel * 65536;
    const float* Bi = sel == 0 ? bk : (sel == 1 ? bq : bv);

    {
        const int cq = t >> 4;
        const int nq = (t & 15) * 4;
#pragma unroll
        for (int p = 0; p < 16; ++p) {
            const int c = p * 16 + cq;
            const float4 v = *reinterpret_cast<const float4*>(
                &X[((size_t)b * CH + c) * NT + n0 + nq]);
            T[nq + 0][c] = (f16)v.x;
            T[nq + 1][c] = (f16)v.y;
            T[nq + 2][c] = (f16)v.z;
            T[nq + 3][c] = (f16)v.w;
        }
    }
    __syncthreads();

    f32x4 acc[4][4] = {};   // [h][nt]

#pragma unroll 2
    for (int ks = 0; ks < 8; ++ks) {
        f16x8 bf[4];
#pragma unroll
        for (int nt = 0; nt < 4; ++nt)
            bf[nt] = *reinterpret_cast<const f16x8*>(
                &T[nt * 16 + lm][ks * 32 + lg * 8]);
#pragma unroll
        for (int h = 0; h < 4; ++h) {
            const f16x8 a = *reinterpret_cast<const f16x8*>(
                &W[(size_t)(h * 64 + w * 16 + lm) * CH + ks * 32 + lg * 8]);
#pragma unroll
            for (int nt = 0; nt < 4; ++nt)
                acc[h][nt] = MFMA16(a, bf[nt], acc[h][nt]);
        }
    }

    const int c_base = w * 16 + lg * 4;
    if (sel < 2) {
        f16* Out = sel == 0 ? Kt : Qt;
#pragma unroll
        for (int h = 0; h < 4; ++h) {
            const float4 b4 = *reinterpret_cast<const float4*>(&Bi[h * 64 + c_base]);
            const float bb[4] = {b4.x, b4.y, b4.z, b4.w};
#pragma unroll
            for (int nt = 0; nt < 4; ++nt) {
                const int n = n0 + nt * 16 + lm;
                f16x4 o = {(f16)(acc[h][nt][0] + bb[0]), (f16)(acc[h][nt][1] + bb[1]),
                           (f16)(acc[h][nt][2] + bb[2]), (f16)(acc[h][nt][3] + bb[3])};
                *reinterpret_cast<f16x4*>(
                    &Out[((size_t)((b * NHEADS + h) * NT + n)) * HC + c_base]) = o;
            }
        }
    } else {
        __syncthreads();   // x-tile dead; reuse SMEM as Vt[256][80]
#pragma unroll
        for (int h = 0; h < 4; ++h)
#pragma unroll
            for (int nt = 0; nt < 4; ++nt)
#pragma unroll
                for (int r = 0; r < 4; ++r)
                    Vt[h * 64 + c_base + r][nt * 16 + lm] = (f16)acc[h][nt][r];
        __syncthreads();
#pragma unroll
        for (int p = 0; p < 8; ++p) {
            const int c  = p * 32 + (t >> 3);
            const int nn = (t & 7) * 8;
            const float bb = Bi[c];
            const f16x8 vv = *reinterpret_cast<const f16x8*>(&Vt[c][nn]);
            f16x8 o;
#pragma unroll
            for (int j = 0; j < 8; ++j) o[j] = (f16)((float)vv[j] + bb);
            *reinterpret_cast<f16x8*>(
                &Vg[((size_t)((b * NHEADS + (c >> 6)) * HC + (c & 63))) * NT
                    + n0 + nn]) = o;
        }
    }
}

// ---------------------------------------------------------------------------
// Flash attention PASS 1: 128-query tiles, cross-block SPLIT-K x4,
// DOUBLE-BUFFERED LDS with ONE barrier per chunk (m97 pattern):
//   stage(i+1, buf^1); compute(buf); __syncthreads();
// The barrier both publishes the prefetch (vmcnt drain) and protects buf
// from the overwrite that happens one iteration later.
// grid 1152 = (18 qt x 4 seg x 16 bh, XCD-mapped), block 256 = 4 waves x 32q.
// ---------------------------------------------------------------------------
__global__ __launch_bounds__(256) void attn_p1(
    const f16* __restrict__ Kt, const f16* __restrict__ Qt,
    const f16* __restrict__ Vg,
    f16* __restrict__ Pa, float* __restrict__ Pm, float* __restrict__ Pl)
{
    __shared__ f16 SM[2][2][4096];   // [buf][K/V][64 rows x 64c], 32 KB

    const int t = threadIdx.x, l = t & 63, w = t >> 6;
    const int col = l & 31, hi = l >> 5;

    const int bid = blockIdx.x;
    const int xcd = bid & 7, idx = bid >> 3;          // 144 per XCD
    const int second = idx >= 72 ? 1 : 0;
    const int bh = 2 * xcd + second;                  // 2 (b,h) pairs per XCD
    const int idx2 = idx - 72 * second;               // 0..71
    const int qt = idx2 >> 2, seg = idx2 & 3;
    const int b = bh >> 2, h = bh & 3;
    const int m0 = qt * 128;

    const size_t bhs = (size_t)(b * NHEADS + h);
    const f16* Kb = Kt + bhs * NT * HC;   // [n][64c]
    const f16* Qb = Qt + bhs * NT * HC;
    const f16* Vb = Vg + bhs * HC * NT;   // [c][n]

    const int srow = l >> 3, su = l & 7, sx = su ^ srow;

    const int q = m0 + w * 32 + col;
    f16x8 qf[4];
#pragma unroll
    for (int cs = 0; cs < 4; ++cs)
        qf[cs] = *reinterpret_cast<const f16x8*>(
            &Qb[(size_t)q * HC + cs * 16 + hi * 8]);

    const f32x16 Z16 = {0,0,0,0,0,0,0,0,0,0,0,0,0,0,0,0};
    f32x16 acc0 = Z16, acc1 = Z16;
    float m_run = -3.0e38f, l_run = 0.0f;

    const int kbase = seg * KSEG;

    auto stage = [&](int kc, int buf) {
        const int half = (w & 1) * 32;
        if (w < 2) {
            const char* src = (const char*)(Kb + (size_t)kc * HC);
            char* dst = (char*)&SM[buf][0][0];
#pragma unroll
            for (int g = 0; g < 4; ++g) {
                const int rb = half + g * 8;
                gload_lds16(src + (size_t)(rb + srow) * 128 + (sx << 4),
                            dst + rb * 128);
            }
        } else {
            const char* src = (const char*)Vb + (size_t)kc * 2;
            char* dst = (char*)&SM[buf][1][0];
#pragma unroll
            for (int g = 0; g < 4; ++g) {
                const int rb = half + g * 8;
                gload_lds16(src + (size_t)(rb + srow) * (NT * 2) + (sx << 4),
                            dst + rb * 128);
            }
        }
    };

    auto rd = [&](const f16* base, int row, int u) -> f16x8 {
        return *reinterpret_cast<const f16x8*>(
            base + row * 64 + ((u ^ (row & 7)) << 3));
    };

    stage(kbase, 0);
    __syncthreads();

    for (int i = 0; i < NSEG; ++i) {
        const int cur = i & 1;
        if (i + 1 < NSEG) stage(kbase + (i + 1) * 64, cur ^ 1);

        const f16* Kc = &SM[cur][0][0];
        const f16* Vc = &SM[cur][1][0];

        f32x16 s0 = Z16, s1 = Z16;
#pragma unroll
        for (int cs = 0; cs < 4; ++cs) {
            const f16x8 k0 = rd(Kc, col,      cs * 2 + hi);
            const f16x8 k1 = rd(Kc, 32 + col, cs * 2 + hi);
            s0 = MFMA32(k0, qf[cs], s0);
            s1 = MFMA32(k1, qf[cs], s1);
        }

        float m8[8];
#pragma unroll
        for (int j = 0; j < 8; ++j)
            m8[j] = fmaxf(fmaxf(s0[2 * j], s0[2 * j + 1]),
                          fmaxf(s1[2 * j], s1[2 * j + 1]));
        float cm = fmaxf(fmaxf(fmaxf(m8[0], m8[1]), fmaxf(m8[2], m8[3])),
                         fmaxf(fmaxf(m8[4], m8[5]), fmaxf(m8[6], m8[7])));
        cm = fmaxf(cm, __shfl_xor(cm, 32));
        if (!__all(cm <= m_run + 8.0f)) {     // defer-max, THR=8
            const float mN = fmaxf(m_run, cm);
            const float fac = __expf(m_run - mN);
#pragma unroll
            for (int r = 0; r < 16; ++r) { acc0[r] *= fac; acc1[r] *= fac; }
            l_run *= fac;
            m_run = mN;
        }
        float p0[16], p1[16];
        float ps0 = 0.f, ps1 = 0.f, ps2 = 0.f, ps3 = 0.f;
#pragma unroll
        for (int r = 0; r < 4; ++r) {
            p0[r]      = __expf(s0[r]      - m_run); ps0 += p0[r];
            p0[r + 4]  = __expf(s0[r + 4]  - m_run); ps1 += p0[r + 4];
            p0[r + 8]  = __expf(s0[r + 8]  - m_run); ps2 += p0[r + 8];
            p0[r + 12] = __expf(s0[r + 12] - m_run); ps3 += p0[r + 12];
            p1[r]      = __expf(s1[r]      - m_run); ps0 += p1[r];
            p1[r + 4]  = __expf(s1[r + 4]  - m_run); ps1 += p1[r + 4];
            p1[r + 8]  = __expf(s1[r + 8]  - m_run); ps2 += p1[r + 8];
            p1[r + 12] = __expf(s1[r + 12] - m_run); ps3 += p1[r + 12];
        }
        l_run += (ps0 + ps1) + (ps2 + ps3);

        unsigned a0[8], a1[8];
#pragma unroll
        for (int j = 0; j < 8; ++j) {
            a0[j] = pkh(p0[2 * j], p0[2 * j + 1]);
            a1[j] = pkh(p1[2 * j], p1[2 * j + 1]);
        }
        swap32(a0[0], a0[2]); swap32(a0[1], a0[3]);
        swap32(a0[4], a0[6]); swap32(a0[5], a0[7]);
        swap32(a1[0], a1[2]); swap32(a1[1], a1[3]);
        swap32(a1[4], a1[6]); swap32(a1[5], a1[7]);
        union BU { unsigned u[4]; f16x8 v; };
        BU fr[4];
        fr[0].u[0] = a0[0]; fr[0].u[1] = a0[1]; fr[0].u[2] = a0[2]; fr[0].u[3] = a0[3];
        fr[1].u[0] = a0[4]; fr[1].u[1] = a0[5]; fr[1].u[2] = a0[6]; fr[1].u[3] = a0[7];
        fr[2].u[0] = a1[0]; fr[2].u[1] = a1[1]; fr[2].u[2] = a1[2]; fr[2].u[3] = a1[3];
        fr[3].u[0] = a1[4]; fr[3].u[1] = a1[5]; fr[3].u[2] = a1[6]; fr[3].u[3] = a1[7];

#pragma unroll
        for (int kk = 0; kk < 4; ++kk) {
            const f16x8 v0 = rd(Vc, col,      kk * 2 + hi);
            const f16x8 v1 = rd(Vc, 32 + col, kk * 2 + hi);
            acc0 = MFMA32(v0, fr[kk].v, acc0);
            acc1 = MFMA32(v1, fr[kk].v, acc1);
        }

        __syncthreads();   // publishes prefetch of buf^1; frees buf for i+1's stage
    }

    // ---- publish normalized partials ------------------------------------
    const float l_full = l_run + __shfl_xor(l_run, 32);
    const float inv = 1.0f / l_full;
    const size_t pq = ((size_t)((seg * 16 + bh) * NQT + qt)) * 128 + w * 32 + col;
    if (hi == 0) { Pm[pq] = m_run; Pl[pq] = l_full; }
    f16* row = Pa + pq * 64;
#pragma unroll
    for (int rq = 0; rq < 4; ++rq) {
        const int c0 = rq * 8 + hi * 4;
        f16x4 o0 = {(f16)(acc0[rq * 4 + 0] * inv), (f16)(acc0[rq * 4 + 1] * inv),
                    (f16)(acc0[rq * 4 + 2] * inv), (f16)(acc0[rq * 4 + 3] * inv)};
        f16x4 o1 = {(f16)(acc1[rq * 4 + 0] * inv), (f16)(acc1[rq * 4 + 1] * inv),
                    (f16)(acc1[rq * 4 + 2] * inv), (f16)(acc1[rq * 4 + 3] * inv)};
        *reinterpret_cast<f16x4*>(row + c0) = o0;
        *reinterpret_cast<f16x4*>(row + 32 + c0) = o1;
    }
}

// ---------------------------------------------------------------------------
// FUSED merge + final conv1x1.  grid (36, 4) = (ntile64, b), block 256.
// Phase 1: 4-way exact merge of Pa partials -> LDS T[64n][256c+pad].
// Phase 2: proj_v3-style GEMM over ALL 4 o-tiles; write Y f32 + bias.
// Eliminates the attn_mg kernel, the Ot buffer, and its 28 MB roundtrip.
// ---------------------------------------------------------------------------
__global__ __launch_bounds__(256) void out_fused(
    const f16* __restrict__ wo16, const float* __restrict__ bo,
    const f16* __restrict__ Pa, const float* __restrict__ Pm,
    const float* __restrict__ Pl, float* __restrict__ Y)
{
    __shared__ f16 T[64][264];   // merged attention output tile [n][c]

    const int t = threadIdx.x, l = t & 63, w = t >> 6;
    const int lm = l & 15, lg = l >> 4;
    const int n0 = blockIdx.x * 64;
    const int b = blockIdx.y;
    const int qt = n0 >> 7, ql0 = n0 & 127;   // 128-query tile / offset within

    // ---- phase 1: merge. thread t: query row n = t>>2, 16 ch c16 = (t&3)*16
    {
        const int n = t >> 2, c16 = (t & 3) * 16;
#pragma unroll
        for (int h = 0; h < 4; ++h) {
            const int bh = b * NHEADS + h;
            size_t ix[NSEGS];
            float m[NSEGS], c[NSEGS];
            float M = -3.0e38f;
#pragma unroll
            for (int s = 0; s < NSEGS; ++s) {
                ix[s] = ((size_t)((s * 16 + bh) * NQT + qt)) * 128 + ql0 + n;
                m[s] = Pm[ix[s]];
                M = fmaxf(M, m[s]);
            }
            float csum = 0.f;
#pragma unroll
            for (int s = 0; s < NSEGS; ++s) {
                c[s] = __expf(m[s] - M) * Pl[ix[s]];
                csum += c[s];
            }
            const float inv = 1.0f / csum;
            float v[16] = {};
#pragma unroll
            for (int s = 0; s < NSEGS; ++s) {
                const f16* r = Pa + ix[s] * 64 + c16;
                const f16x8 a0 = *reinterpret_cast<const f16x8*>(r);
                const f16x8 a1 = *reinterpret_cast<const f16x8*>(r + 8);
#pragma unroll
                for (int j = 0; j < 8; ++j) {
                    v[j]     += c[s] * (float)a0[j];
                    v[8 + j] += c[s] * (float)a1[j];
                }
            }
            f16x8 o0, o1;
#pragma unroll
            for (int j = 0; j < 8; ++j) {
                o0[j] = (f16)(v[j] * inv);
                o1[j] = (f16)(v[8 + j] * inv);
            }
            *reinterpret_cast<f16x8*>(&T[n][h * 64 + c16]) = o0;
            *reinterpret_cast<f16x8*>(&T[n][h * 64 + c16 + 8]) = o1;
        }
    }
    __syncthreads();

    // ---- phase 2: GEMM (proj_v3 structure), all 4 o-tiles ----------------
    f32x4 acc[4][4] = {};   // [h'][nt]
#pragma unroll 2
    for (int ks = 0; ks < 8; ++ks) {
        f16x8 bf[4];
#pragma unroll
        for (int nt = 0; nt < 4; ++nt)
            bf[nt] = *reinterpret_cast<const f16x8*>(
                &T[nt * 16 + lm][ks * 32 + lg * 8]);
#pragma unroll
        for (int hp = 0; hp < 4; ++hp) {
            const f16x8 a = *reinterpret_cast<const f16x8*>(
                &wo16[(size_t)(hp * 64 + w * 16 + lm) * CH + ks * 32 + lg * 8]);
#pragma unroll
            for (int nt = 0; nt < 4; ++nt)
                acc[hp][nt] = MFMA16(a, bf[nt], acc[hp][nt]);
        }
    }

    const int c_base = w * 16 + lg * 4;
#pragma unroll
    for (int hp = 0; hp < 4; ++hp) {
        const float4 b4 = *reinterpret_cast<const float4*>(&bo[hp * 64 + c_base]);
        const float bb[4] = {b4.x, b4.y, b4.z, b4.w};
#pragma unroll
        for (int nt = 0; nt < 4; ++nt) {
            const int n = n0 + nt * 16 + lm;
#pragma unroll
            for (int r = 0; r < 4; ++r)
                Y[((size_t)(b * CH + hp * 64 + c_base + r)) * NT + n] =
                    acc[hp][nt][r] + bb[r];
        }
    }
}

// ---------------------------------------------------------------------------
extern "C" void kernel_launch(void* const* d_in, const int* in_sizes, int n_in,
                              void* d_out, int out_size, void* d_ws, size_t ws_size,
                              hipStream_t stream) {
    (void)in_sizes; (void)n_in; (void)out_size; (void)ws_size;
    const float* x  = (const float*)d_in[0];
    const float* wk = (const float*)d_in[1];
    const float* bk = (const float*)d_in[2];
    const float* wq = (const float*)d_in[3];
    const float* bq = (const float*)d_in[4];
    const float* wv = (const float*)d_in[5];
    const float* bv = (const float*)d_in[6];
    const float* wo = (const float*)d_in[7];
    const float* bo = (const float*)d_in[8];
    float* out = (float*)d_out;

    const size_t SZ = (size_t)NB * NT * CH;           // 2,359,296 f16 per tensor
    f16* Kt  = (f16*)d_ws;                            // [b][h][n][c]
    f16* Qt  = Kt + SZ;                               // [b][h][n][c]
    f16* Vg  = Qt + SZ;                               // [b][h][c][n]
    f16* W16 = Vg + SZ;                               // [4][65536] f16
    f16* Pa  = W16 + 4 * 65536;                       // [4][16][18][128][64] f16
    float* Pm = (float*)(Pa + (size_t)NSEGS * 16 * NQT * 128 * 64);
    float* Pl = Pm + (size_t)NSEGS * 16 * NQT * 128;  // total ws ~34 MB

    wcvt<<<dim3(128), 256, 0, stream>>>(wk, wq, wv, wo, W16);
    proj_qkv_v3<<<dim3(36, 3, 4), 256, 0, stream>>>(
        W16, bk, bq, bv, x, Kt, Qt, Vg);
    attn_p1<<<dim3(1152), 256, 0, stream>>>(Kt, Qt, Vg, Pa, Pm, Pl);
    out_fused<<<dim3(36, 4), 256, 0, stream>>>(
        W16 + 3 * 65536, bo, Pa, Pm, Pl, out);
}